// Round 8
// baseline (761.964 us; speedup 1.0000x reference)
//
#include <hip/hip_runtime.h>
#include <stdint.h>
#include <math.h>

#define NN   100000
#define FIN  128
#define HIDDEN 256
#define NCLS 40
#define NE   1600000

// CSR bucketing: P node-ranges x S edge-slices
#define PRNG 8
#define RNG  12500          // NN / PRNG
#define SSL  32
#define NES  50000          // NE / SSL

typedef unsigned short u16;
typedef unsigned char u8;
typedef __attribute__((ext_vector_type(8))) short s16x8;
typedef __attribute__((ext_vector_type(4))) float f32x4;
typedef __attribute__((ext_vector_type(2))) float f32x2;

__device__ __forceinline__ float bf2f(unsigned short u) {
    union { float f; uint32_t i; } v; v.i = ((uint32_t)u) << 16; return v.f;
}
__device__ __forceinline__ unsigned short f2bf(float f) {
    union { float f; uint32_t i; } v; v.f = f;
    uint32_t r = v.i + 0x7fffu + ((v.i >> 16) & 1u);
    return (unsigned short)(r >> 16);
}
__device__ __forceinline__ u8 f2fp8(float f) {
    int r = __builtin_amdgcn_cvt_pk_fp8_f32(f, f, 0, false);
    return (u8)(r & 0xff);
}

// ---------------- dtype detection (parallel, 64 blocks) ----------------
// flags[0] != 0 => float tensors are float32 (else bf16)
// flags[2] == 0 => edge_index int64 (all odd i32 words zero), else int32
__global__ __launch_bounds__(256) void k_detect(const u16* __restrict__ x16,
                                                const int* __restrict__ ei,
                                                int* __restrict__ flags) {
    int g = blockIdx.x * 256 + threadIdx.x;      // 0..16383
    uint2 v = *(const uint2*)(x16 + (size_t)g * 4);
    int nan_cnt = 0;
    uint32_t w0 = v.x, w1 = v.y;
    if (((w0 >> 0)  & 0x7fff) >= 0x7f80) nan_cnt++;
    if (((w0 >> 16) & 0x7fff) >= 0x7f80) nan_cnt++;
    if (((w1 >> 0)  & 0x7fff) >= 0x7f80) nan_cnt++;
    if (((w1 >> 16) & 0x7fff) >= 0x7f80) nan_cnt++;
    int odd_nz = (g < 8192 && ei[2 * g + 1] != 0) ? 1 : 0;
#pragma unroll
    for (int off = 1; off < 64; off <<= 1) {
        nan_cnt += __shfl_xor(nan_cnt, off);
        odd_nz  += __shfl_xor(odd_nz, off);
    }
    if ((threadIdx.x & 63) == 0) {
        if (nan_cnt) atomicAdd(&flags[0], nan_cnt);
        if (odd_nz)  atomicAdd(&flags[2], odd_nz);
    }
}

// edge_index -> dense i32 dst/src (handles both i64 and i32 storage)
__global__ void k_compact(const int* __restrict__ ei, int* __restrict__ dst32,
                          int* __restrict__ src32, const int* __restrict__ flags) {
    int e = blockIdx.x * 256 + threadIdx.x;
    if (e < NE) {
        if (flags[2] == 0) { src32[e] = ei[2 * e]; dst32[e] = ei[2 * (NE + e)]; }
        else               { src32[e] = ei[e];     dst32[e] = ei[NE + e]; }
    }
}

// weights transpose + bias cvt + x cvt (prescaled by dinv, VECTORIZED x8), one launch
__global__ void k_trans_cvt(const void* W1, const void* W2, const void* W3, const void* W4,
                            u16* W1t, u16* W2t, u16* W3t, u16* W4t,
                            const void* b1, const void* b2, const void* b3, const void* b4,
                            u16* o1, u16* o2, u16* o3, u16* o4,
                            const void* __restrict__ x, const float* __restrict__ dinv,
                            u16* __restrict__ xb,
                            const int* __restrict__ flags) {
    int b = blockIdx.x;
    int fl = flags[0];
    int t = threadIdx.x;
    if (b >= 705) {            // x convert: 6250 blocks, 8 elems/thread
        int i8 = (b - 705) * 256 + t;
        if (i8 < NN * FIN / 8) {
            int i = i8 * 8;
            float d = dinv[i >> 7];          // 8 elems within one row (128 % 8 == 0)
            u16 r[8];
            if (fl) {
                const float* xf = (const float*)x + i;
                f32x4 v0 = *(const f32x4*)xf;
                f32x4 v1 = *(const f32x4*)(xf + 4);
#pragma unroll
                for (int k = 0; k < 4; ++k) { r[k] = f2bf(v0[k] * d); r[4 + k] = f2bf(v1[k] * d); }
            } else {
                uint4 v = *(const uint4*)((const u16*)x + i);
                uint32_t w[4] = {v.x, v.y, v.z, v.w};
#pragma unroll
                for (int k = 0; k < 4; ++k) {
                    r[2 * k]     = f2bf(bf2f((u16)(w[k] & 0xffff)) * d);
                    r[2 * k + 1] = f2bf(bf2f((u16)(w[k] >> 16)) * d);
                }
            }
            uint4 o;
            o.x = (uint32_t)r[0] | ((uint32_t)r[1] << 16);
            o.y = (uint32_t)r[2] | ((uint32_t)r[3] << 16);
            o.z = (uint32_t)r[4] | ((uint32_t)r[5] << 16);
            o.w = (uint32_t)r[6] | ((uint32_t)r[7] << 16);
            *(uint4*)(xb + i) = o;
        }
        return;
    }
    if (b == 704) {
        o1[t] = fl ? f2bf(((const float*)b1)[t]) : ((const u16*)b1)[t];
        o2[t] = fl ? f2bf(((const float*)b2)[t]) : ((const u16*)b2)[t];
        o3[t] = fl ? f2bf(((const float*)b3)[t]) : ((const u16*)b3)[t];
        if (t < 64) o4[t] = (t < NCLS) ? (fl ? f2bf(((const float*)b4)[t]) : ((const u16*)b4)[t]) : (u16)0;
        return;
    }
    const void* W; u16* Wt; int K, F, Fpad, base;
    if (b < 128)      { W = W1; Wt = W1t; K = 128; F = 256; Fpad = 256; base = 0; }
    else if (b < 384) { W = W2; Wt = W2t; K = 256; F = 256; Fpad = 256; base = 128; }
    else if (b < 640) { W = W3; Wt = W3t; K = 256; F = 256; Fpad = 256; base = 384; }
    else              { W = W4; Wt = W4t; K = 256; F = 40;  Fpad = 64;  base = 640; }
    int idx = (b - base) * 256 + t;
    if (idx >= K * Fpad) return;
    int f = idx / K, k = idx - f * K;
    u16 v = 0;
    if (f < F) {
        if (fl) v = f2bf(((const float*)W)[(size_t)k * F + f]);
        else    v = ((const u16*)W)[(size_t)k * F + f];
    }
    Wt[idx] = v;
}

// ---------------- CSR build (no device atomics; i32 inputs) ----------------

__global__ __launch_bounds__(256) void k_histb(const int* __restrict__ dst32,
                                               int* __restrict__ partial) {
    __shared__ int h[RNG];
    int p = blockIdx.x >> 5, s = blockIdx.x & 31;
    int t = threadIdx.x;
    int4 z4 = make_int4(0, 0, 0, 0);
    for (int i = t * 4; i < RNG; i += 1024) *(int4*)(h + i) = z4;
    __syncthreads();
    int base = s * NES;
    int lo = p * RNG;
    int nfull = NES & ~1023;
    for (int k = t * 4; k < nfull; k += 1024) {
        int4 d4 = *(const int4*)(dst32 + base + k);
        int a;
        a = d4.x - lo; if ((unsigned)a < RNG) atomicAdd(&h[a], 1);
        a = d4.y - lo; if ((unsigned)a < RNG) atomicAdd(&h[a], 1);
        a = d4.z - lo; if ((unsigned)a < RNG) atomicAdd(&h[a], 1);
        a = d4.w - lo; if ((unsigned)a < RNG) atomicAdd(&h[a], 1);
    }
    for (int k = nfull + t; k < NES; k += 256) {
        int a = dst32[base + k] - lo;
        if ((unsigned)a < RNG) atomicAdd(&h[a], 1);
    }
    __syncthreads();
    int* out = partial + blockIdx.x * RNG;
    for (int i = t * 4; i < RNG; i += 1024) *(int4*)(out + i) = *(const int4*)(h + i);
}

// fused: per-node degree (sum of 32 partial slices) + block-local exclusive prefix
__global__ __launch_bounds__(256) void k_scan1(const int* __restrict__ partial,
                                               int* __restrict__ cnt,
                                               int* __restrict__ out,
                                               int* __restrict__ bsum) {
    __shared__ int sh[256];
    int t = threadIdx.x;
    int base = blockIdx.x * 1024 + t * 4;
    int v0 = 0, v1 = 0, v2 = 0, v3 = 0;
    if (base < NN) {
        int p = base / RNG, il = base - p * RNG;
        const int* q = partial + (p * SSL) * RNG + il;
        int4 acc = make_int4(0, 0, 0, 0);
#pragma unroll
        for (int s = 0; s < SSL; ++s) {
            int4 w = *(const int4*)(q + s * RNG);
            acc.x += w.x; acc.y += w.y; acc.z += w.z; acc.w += w.w;
        }
        v0 = acc.x; v1 = acc.y; v2 = acc.z; v3 = acc.w;
        *(int4*)(cnt + base) = acc;
    }
    int s = v0 + v1 + v2 + v3;
    sh[t] = s;
    __syncthreads();
    for (int off = 1; off < 256; off <<= 1) {
        int x = (t >= off) ? sh[t - off] : 0;
        __syncthreads();
        sh[t] += x;
        __syncthreads();
    }
    int ex = sh[t] - s;
    if (base < NN) {
        int4 o = make_int4(ex, ex + v0, ex + v0 + v1, ex + v0 + v1 + v2);
        *(int4*)(out + base) = o;
    }
    if (t == 255) bsum[blockIdx.x] = sh[255];
}

// parallel exclusive scan of nb (<=128) block sums — replaces the serial 1-thread loop
__global__ void k_scan2(int* bsum, int nb) {
    __shared__ int sh[128];
    int t = threadIdx.x;
    int v = (t < nb) ? bsum[t] : 0;
    sh[t] = v;
    __syncthreads();
    for (int off = 1; off < 128; off <<= 1) {
        int x = (t >= off) ? sh[t - off] : 0;
        __syncthreads();
        sh[t] += x;
        __syncthreads();
    }
    if (t < nb) bsum[t] = sh[t] - v;
}

// finalize rp, dinv, and convert partial -> absolute slice offsets
__global__ void k_scan3o(int* __restrict__ rp, const int* __restrict__ bsum,
                         const int* __restrict__ cnt, float* __restrict__ dinv,
                         int* __restrict__ partial) {
    int i = blockIdx.x * 256 + threadIdx.x;
    if (i < NN) {
        int v = rp[i] + bsum[i >> 10];
        rp[i] = v;
        dinv[i] = rsqrtf((float)(cnt[i] + 1));
        int p = i / RNG, il = i - p * RNG;
        int* q = partial + (p * SSL) * RNG + il;
        int run = v;
#pragma unroll
        for (int s = 0; s < SSL; ++s) { int t = q[s * RNG]; q[s * RNG] = run; run += t; }
    }
    if (i == 0) rp[NN] = NE;
}

__global__ __launch_bounds__(256) void k_fillb(const int* __restrict__ dst32,
                                               const int* __restrict__ src32,
                                               const int* __restrict__ offs,
                                               int* __restrict__ col) {
    __shared__ int h[RNG];
    int p = blockIdx.x >> 5, s = blockIdx.x & 31;
    int t = threadIdx.x;
    const int* o = offs + blockIdx.x * RNG;
    for (int i = t * 4; i < RNG; i += 1024) *(int4*)(h + i) = *(const int4*)(o + i);
    __syncthreads();
    int base = s * NES;
    int lo = p * RNG;
    int nfull = NES & ~1023;
    for (int k = t * 4; k < nfull; k += 1024) {
        int4 d4 = *(const int4*)(dst32 + base + k);
        int4 s4 = *(const int4*)(src32 + base + k);
        int a;
        a = d4.x - lo; if ((unsigned)a < RNG) col[atomicAdd(&h[a], 1)] = s4.x;
        a = d4.y - lo; if ((unsigned)a < RNG) col[atomicAdd(&h[a], 1)] = s4.y;
        a = d4.z - lo; if ((unsigned)a < RNG) col[atomicAdd(&h[a], 1)] = s4.z;
        a = d4.w - lo; if ((unsigned)a < RNG) col[atomicAdd(&h[a], 1)] = s4.w;
    }
    for (int k = nfull + t; k < NES; k += 256) {
        int a = dst32[base + k] - lo;
        if ((unsigned)a < RNG) col[atomicAdd(&h[a], 1)] = src32[base + k];
    }
}

// ---------------- Persistent-B GEMM (N=256 halves): C = epi(A @ Wt^T) ----------------
// out_fp8: write hs as fp8 e4m3 (for the gather kernels); else bf16.
// grid (128,2): 256 wg = exactly 1 block/CU (82KB LDS) -> Bs loaded once, 6-7 tile stride.

#define GLL(g, l) __builtin_amdgcn_global_load_lds( \
    (const __attribute__((address_space(1))) unsigned int*)(g), \
    (__attribute__((address_space(3))) unsigned int*)(l), 16, 0, 0)

#define NT128 ((NN + 127) / 128)
#define NT256 ((NN + 255) / 256)

__global__ __launch_bounds__(256) void k_gemmP(const u16* __restrict__ A,
                                               const u16* __restrict__ Wt,
                                               const float* __restrict__ dinv,
                                               const u16* __restrict__ bias,
                                               u16* __restrict__ C,
                                               int K, int out_fp8) {
    __shared__ __align__(16) u16 Bs[128 * 256];   // blocked [K/32][128][32]
    __shared__ __align__(16) u16 As[2 * 128 * 32];
    int t = threadIdx.x;
    int bn = blockIdx.y;
    int w = t >> 6, lane = t & 63;
    int wm = w >> 1, wn = w & 1;
    int lrow = lane & 15, lq = lane >> 4;
    int r0 = t >> 2;
    int seg = (t & 3) * 8;

    int rounds = K >> 4;
    for (int r = 0; r < rounds; ++r) {
        int d = r * 4096 + t * 16;
        int kt = d >> 13;
        int win = d & 8191;
        int row = win >> 6;
        int sg = (win & 63) >> 1;
        GLL(Wt + (size_t)(bn * 128 + row) * K + kt * 32 + sg, Bs + (d >> 1));
    }

    int nK = K >> 5;
    bool fuse = (bias != nullptr);
    float bcol[4];
#pragma unroll
    for (int j = 0; j < 4; ++j)
        bcol[j] = fuse ? bf2f(bias[bn * 128 + wn * 64 + j * 16 + lrow]) : 0.f;

    for (int tm = blockIdx.x; tm < NT128; tm += gridDim.x) {
        int rowBase = tm * 128;
        int ar0 = rowBase + r0;       if (ar0 > NN - 1) ar0 = NN - 1;
        int ar1 = rowBase + 64 + r0;  if (ar1 > NN - 1) ar1 = NN - 1;
        const u16* a0p = A + (size_t)ar0 * K + seg;
        const u16* a1p = A + (size_t)ar1 * K + seg;
        GLL(a0p, As + t * 8);
        GLL(a1p, As + 2048 + t * 8);

        f32x4 acc[4][4] = {};
        int cur = 0;
        for (int kt = 0; kt < nK; ++kt) {
            __syncthreads();
            if (kt + 1 < nK) {
                int nxt = cur ^ 1;
                GLL(a0p + (kt + 1) * 32, As + nxt * 4096 + t * 8);
                GLL(a1p + (kt + 1) * 32, As + nxt * 4096 + 2048 + t * 8);
            }
            const u16* ab = As + cur * 4096;
            const u16* bb = Bs + kt * 4096;
            s16x8 af[4], bf[4];
#pragma unroll
            for (int i = 0; i < 4; ++i)
                af[i] = *(const s16x8*)(ab + (wm * 64 + i * 16 + lrow) * 32 + lq * 8);
#pragma unroll
            for (int j = 0; j < 4; ++j)
                bf[j] = *(const s16x8*)(bb + (wn * 64 + j * 16 + lrow) * 32 + lq * 8);
#pragma unroll
            for (int i = 0; i < 4; ++i)
#pragma unroll
                for (int j = 0; j < 4; ++j)
                    acc[i][j] = __builtin_amdgcn_mfma_f32_16x16x32_bf16(af[i], bf[j], acc[i][j], 0, 0, 0);
            cur ^= 1;
        }

        u8* C8 = (u8*)C;
#pragma unroll
        for (int i = 0; i < 4; ++i) {
#pragma unroll
            for (int rr = 0; rr < 4; ++rr) {
                int row = rowBase + wm * 64 + i * 16 + lq * 4 + rr;
                if (row < NN) {
                    float d = dinv[row];
#pragma unroll
                    for (int j = 0; j < 4; ++j) {
                        int colg = bn * 128 + wn * 64 + j * 16 + lrow;
                        float v = fuse ? fmaxf(fmaf(d, acc[i][j][rr], bcol[j]), 0.f)
                                       : acc[i][j][rr] * d;
                        if (out_fp8) C8[(size_t)row * HIDDEN + colg] = f2fp8(v);
                        else         C[(size_t)row * HIDDEN + colg] = f2bf(v);
                    }
                }
            }
        }
        __syncthreads();
    }
}

// ---------------- Persistent-B GEMM conv5: 256-row x 64-col tiles, K=256 ----------------
__global__ __launch_bounds__(256) void k_gemmP64(const u16* __restrict__ A,
                                                 const u16* __restrict__ Wt,
                                                 const float* __restrict__ dinv,
                                                 u16* __restrict__ C) {
    const int K = 256;
    __shared__ __align__(16) u16 Bs[64 * 256];
    __shared__ __align__(16) u16 As[2 * 256 * 32];
    int t = threadIdx.x;
    int w = t >> 6, lane = t & 63;
    int lrow = lane & 15, lq = lane >> 4;
    int seg = (t & 3) * 8;
    int rr0 = t >> 2;

    for (int r = 0; r < 8; ++r)
        GLL(Wt + (size_t)(t >> 2) * K + r * 32 + seg, Bs + r * 2048 + t * 8);

    for (int tm = blockIdx.x; tm < NT256; tm += gridDim.x) {
        int rowBase = tm * 256;
        const u16* ap[4];
#pragma unroll
        for (int c = 0; c < 4; ++c) {
            int ar = rowBase + c * 64 + rr0;
            if (ar > NN - 1) ar = NN - 1;
            ap[c] = A + (size_t)ar * K + seg;
        }
#pragma unroll
        for (int c = 0; c < 4; ++c) GLL(ap[c], As + c * 2048 + t * 8);

        f32x4 acc[4][4] = {};
        int cur = 0;
        for (int kt = 0; kt < 8; ++kt) {
            __syncthreads();
            if (kt + 1 < 8) {
                int nxt = cur ^ 1;
#pragma unroll
                for (int c = 0; c < 4; ++c)
                    GLL(ap[c] + (kt + 1) * 32, As + nxt * 8192 + c * 2048 + t * 8);
            }
            const u16* ab = As + cur * 8192;
            const u16* bb = Bs + kt * 2048;
            s16x8 af[4], bf[4];
#pragma unroll
            for (int i = 0; i < 4; ++i)
                af[i] = *(const s16x8*)(ab + (w * 64 + i * 16 + lrow) * 32 + lq * 8);
#pragma unroll
            for (int j = 0; j < 4; ++j)
                bf[j] = *(const s16x8*)(bb + (j * 16 + lrow) * 32 + lq * 8);
#pragma unroll
            for (int i = 0; i < 4; ++i)
#pragma unroll
                for (int j = 0; j < 4; ++j)
                    acc[i][j] = __builtin_amdgcn_mfma_f32_16x16x32_bf16(af[i], bf[j], acc[i][j], 0, 0, 0);
            cur ^= 1;
        }

#pragma unroll
        for (int i = 0; i < 4; ++i) {
#pragma unroll
            for (int rr = 0; rr < 4; ++rr) {
                int row = rowBase + w * 64 + i * 16 + lq * 4 + rr;
                if (row < NN) {
                    float d = dinv[row];
#pragma unroll
                    for (int j = 0; j < 4; ++j) {
                        int colg = j * 16 + lrow;
                        C[(size_t)row * 64 + colg] = f2bf(acc[i][j][rr] * d);
                    }
                }
            }
        }
        __syncthreads();
    }
}

// ---------------- aggregation F=256 over fp8 hs (convs 2-4) ----------------
// feature-parallel full wave: lane owns 4 fp8 features (4 B), wave walks edges.
// row/p/col are wave-uniform -> scalar loads; 8 gathers in flight (measured optimum).

__global__ __launch_bounds__(256) void k_agg8(const u8* __restrict__ hs,
                                              const int* __restrict__ rp,
                                              const int* __restrict__ col,
                                              const float* __restrict__ dinv,
                                              const u16* __restrict__ bias,
                                              u16* __restrict__ out) {
    int wq = __builtin_amdgcn_readfirstlane(threadIdx.x >> 6);
    int row = blockIdx.x * 4 + wq;
    if (row >= NN) return;
    int lane = threadIdx.x & 63;
    int fo = lane * 4;                  // feature offset (fp8: bytes == features)
    float a0 = 0.f, a1 = 0.f, a2 = 0.f, a3 = 0.f;
    auto acc_add = [&](uint32_t w) {
        f32x2 x = __builtin_amdgcn_cvt_pk_f32_fp8(w, false);
        f32x2 y = __builtin_amdgcn_cvt_pk_f32_fp8(w, true);
        a0 += x.x; a1 += x.y; a2 += y.x; a3 += y.y;
    };
    auto acc_fma = [&](uint32_t w, float m) {
        f32x2 x = __builtin_amdgcn_cvt_pk_f32_fp8(w, false);
        f32x2 y = __builtin_amdgcn_cvt_pk_f32_fp8(w, true);
        a0 = fmaf(m, x.x, a0); a1 = fmaf(m, x.y, a1);
        a2 = fmaf(m, y.x, a2); a3 = fmaf(m, y.y, a3);
    };
    acc_add(*(const uint32_t*)(hs + (size_t)row * HIDDEN + fo));   // self loop
    int p  = __builtin_amdgcn_readfirstlane(rp[row]);
    int p1 = __builtin_amdgcn_readfirstlane(rp[row + 1]);
    for (; p + 8 <= p1; p += 8) {
        uint32_t v[8];
#pragma unroll
        for (int k = 0; k < 8; ++k) {
            int c = __builtin_amdgcn_readfirstlane(col[p + k]);
            v[k] = *(const uint32_t*)(hs + (size_t)c * HIDDEN + fo);
        }
#pragma unroll
        for (int k = 0; k < 8; ++k) acc_add(v[k]);
    }
    int rem = p1 - p;                   // 0..7, wave-uniform
    if (rem) {
        uint32_t v[8];
#pragma unroll
        for (int k = 0; k < 8; ++k) {
            int idx = (k < rem) ? (p + k) : p;
            int c = __builtin_amdgcn_readfirstlane(col[idx]);
            v[k] = *(const uint32_t*)(hs + (size_t)c * HIDDEN + fo);
        }
#pragma unroll
        for (int k = 0; k < 8; ++k) acc_fma(v[k], (k < rem) ? 1.f : 0.f);
    }
    float d = dinv[row];
    uint2 bv = *(const uint2*)(bias + fo);
    float r0 = fmaxf(fmaf(d, a0, bf2f((u16)(bv.x & 0xffff))), 0.f);
    float r1 = fmaxf(fmaf(d, a1, bf2f((u16)(bv.x >> 16))), 0.f);
    float r2 = fmaxf(fmaf(d, a2, bf2f((u16)(bv.y & 0xffff))), 0.f);
    float r3 = fmaxf(fmaf(d, a3, bf2f((u16)(bv.y >> 16))), 0.f);
    uint2 o;
    o.x = (uint32_t)f2bf(r0) | ((uint32_t)f2bf(r1) << 16);
    o.y = (uint32_t)f2bf(r2) | ((uint32_t)f2bf(r3) << 16);
    *(uint2*)(out + (size_t)row * HIDDEN + fo) = o;
}

// ---------------- conv1 pre-aggregation on prescaled x (128 features, bf16) ----------------
// feature-parallel: lane owns 2 bf16 features (4 B), wave walks edges; 8 in flight.
__global__ __launch_bounds__(256) void k_aggx(const u16* __restrict__ xb,
                                              const int* __restrict__ rp,
                                              const int* __restrict__ col,
                                              u16* __restrict__ out) {
    int wq = __builtin_amdgcn_readfirstlane(threadIdx.x >> 6);
    int row = blockIdx.x * 4 + wq;
    if (row >= NN) return;
    int lane = threadIdx.x & 63;
    int fo = lane * 2;                  // u16 index: 2 bf16 per lane
    float a0 = 0.f, a1 = 0.f;
    auto acc_add = [&](uint32_t w) {
        a0 += bf2f((u16)(w & 0xffff));
        a1 += bf2f((u16)(w >> 16));
    };
    auto acc_fma = [&](uint32_t w, float m) {
        a0 = fmaf(m, bf2f((u16)(w & 0xffff)), a0);
        a1 = fmaf(m, bf2f((u16)(w >> 16)), a1);
    };
    acc_add(*(const uint32_t*)(xb + (size_t)row * FIN + fo));      // self loop
    int p  = __builtin_amdgcn_readfirstlane(rp[row]);
    int p1 = __builtin_amdgcn_readfirstlane(rp[row + 1]);
    for (; p + 8 <= p1; p += 8) {
        uint32_t v[8];
#pragma unroll
        for (int k = 0; k < 8; ++k) {
            int c = __builtin_amdgcn_readfirstlane(col[p + k]);
            v[k] = *(const uint32_t*)(xb + (size_t)c * FIN + fo);
        }
#pragma unroll
        for (int k = 0; k < 8; ++k) acc_add(v[k]);
    }
    int rem = p1 - p;
    if (rem) {
        uint32_t v[8];
#pragma unroll
        for (int k = 0; k < 8; ++k) {
            int idx = (k < rem) ? (p + k) : p;
            int c = __builtin_amdgcn_readfirstlane(col[idx]);
            v[k] = *(const uint32_t*)(xb + (size_t)c * FIN + fo);
        }
#pragma unroll
        for (int k = 0; k < 8; ++k) acc_fma(v[k], (k < rem) ? 1.f : 0.f);
    }
    uint32_t o = (uint32_t)f2bf(a0) | ((uint32_t)f2bf(a1) << 16);
    *(uint32_t*)(out + (size_t)row * FIN + fo) = o;
}

// ---------------- last layer: hs padded to 64 cols (bf16); agg + bias + log_softmax ----------------
// feature-parallel: lane owns 1 class (2 B), wave walks edges; softmax across lanes.
__global__ __launch_bounds__(256) void k_agg5(const u16* __restrict__ hs,
                                              const int* __restrict__ rp,
                                              const int* __restrict__ col,
                                              const float* __restrict__ dinv,
                                              const u16* __restrict__ bias,
                                              void* __restrict__ out,
                                              const int* __restrict__ flags) {
    int wq = __builtin_amdgcn_readfirstlane(threadIdx.x >> 6);
    int row = blockIdx.x * 4 + wq;
    if (row >= NN) return;
    int lane = threadIdx.x & 63;
    float a = bf2f(hs[(size_t)row * 64 + lane]);                   // self loop
    int p  = __builtin_amdgcn_readfirstlane(rp[row]);
    int p1 = __builtin_amdgcn_readfirstlane(rp[row + 1]);
    for (; p + 8 <= p1; p += 8) {
        u16 v[8];
#pragma unroll
        for (int k = 0; k < 8; ++k) {
            int c = __builtin_amdgcn_readfirstlane(col[p + k]);
            v[k] = hs[(size_t)c * 64 + lane];
        }
#pragma unroll
        for (int k = 0; k < 8; ++k) a += bf2f(v[k]);
    }
    int rem = p1 - p;
    if (rem) {
        u16 v[8];
#pragma unroll
        for (int k = 0; k < 8; ++k) {
            int idx = (k < rem) ? (p + k) : p;
            int c = __builtin_amdgcn_readfirstlane(col[idx]);
            v[k] = hs[(size_t)c * 64 + lane];
        }
#pragma unroll
        for (int k = 0; k < 8; ++k)
            a = fmaf((k < rem) ? 1.f : 0.f, bf2f(v[k]), a);
    }
    bool act = lane < NCLS;
    float d = dinv[row];
    float l = act ? fmaf(d, a, bf2f(bias[lane])) : -1e30f;
    float m = l;
#pragma unroll
    for (int off = 32; off > 0; off >>= 1) m = fmaxf(m, __shfl_xor(m, off));
    float e = act ? __expf(l - m) : 0.f;
#pragma unroll
    for (int off = 32; off > 0; off >>= 1) e += __shfl_xor(e, off);
    if (act) {
        float r = l - m - __logf(e);
        if (flags[0]) ((float*)out)[(size_t)row * NCLS + lane] = r;
        else          ((u16*)out)[(size_t)row * NCLS + lane] = f2bf(r);
    }
}

// ---------------- launch ----------------

extern "C" void kernel_launch(void* const* d_in, const int* in_sizes, int n_in,
                              void* d_out, int out_size, void* d_ws, size_t ws_size,
                              hipStream_t stream) {
    const void* x  = d_in[0];
    const int* ei  = (const int*)d_in[1];
    const void* W1 = d_in[2];
    const void* b1 = d_in[3];
    const void* W2 = d_in[4];
    const void* b2 = d_in[5];
    const void* W3 = d_in[6];
    const void* b3 = d_in[7];
    const void* W4 = d_in[8];
    const void* b4 = d_in[9];

    char* p = (char*)d_ws;
    auto alloc = [&](size_t b) -> char* {
        char* r = p;
        p += (b + 255) & ~(size_t)255;
        return r;
    };
    int*   flags = (int*)alloc(256);
    int*   cnt  = (int*)alloc((size_t)NN * 4);
    float* dinv = (float*)alloc((size_t)NN * 4);
    int*   rp   = (int*)alloc((size_t)(NN + 1) * 4);
    int*   col  = (int*)alloc((size_t)NE * 4);
    int*   bsum = (int*)alloc(4096);
    u16* xb  = (u16*)alloc((size_t)NN * FIN * 2);
    u16* W1t = (u16*)alloc((size_t)256 * 128 * 2);
    u16* W2t = (u16*)alloc((size_t)256 * 256 * 2);
    u16* W3t = (u16*)alloc((size_t)256 * 256 * 2);
    u16* W4t = (u16*)alloc((size_t)64 * 256 * 2);
    u16* bb1 = (u16*)alloc(512);
    u16* bb2 = (u16*)alloc(512);
    u16* bb3 = (u16*)alloc(512);
    u16* bb4 = (u16*)alloc(128);
    u16* bufA = (u16*)alloc((size_t)NN * HIDDEN * 2);
    u16* bufB = (u16*)alloc((size_t)NN * HIDDEN * 2);

    // CSR-build scratch aliased into conv buffers (dead before conv use)
    int* dst32   = (int*)bufA;                    // 6.4 MB
    int* src32   = dst32 + NE;                    // 6.4 MB
    int* partial = (int*)bufB;                    // 12.8 MB

    hipMemsetAsync(flags, 0, 16, stream);
    k_detect<<<64, 256, 0, stream>>>((const u16*)x, ei, flags);
    k_compact<<<(NE + 255) / 256, 256, 0, stream>>>(ei, dst32, src32, flags);

    // CSR build (atomic-free at device scope, i32 streams)
    k_histb<<<PRNG * SSL, 256, 0, stream>>>(dst32, partial);
    k_scan1<<<(NN + 1023) / 1024, 256, 0, stream>>>(partial, cnt, rp, bsum);
    k_scan2<<<1, 128, 0, stream>>>(bsum, (NN + 1023) / 1024);
    k_scan3o<<<(NN + 255) / 256, 256, 0, stream>>>(rp, bsum, cnt, dinv, partial);
    k_fillb<<<PRNG * SSL, 256, 0, stream>>>(dst32, src32, partial, col);

    // weights/bias transpose + x convert (prescaled by dinv, vectorized), one launch
    k_trans_cvt<<<705 + (NN * FIN / 8 + 255) / 256, 256, 0, stream>>>(
        W1, W2, W3, W4, W1t, W2t, W3t, W4t,
        b1, b2, b3, b4, bb1, bb2, bb3, bb4, x, dinv, xb, flags);

    dim3 gP(128, 2);                    // 256 wg = 1/CU; Bs loaded once per block
    dim3 aggGrid((NN + 3) / 4);

    // conv1 (aggregate-then-transform): y = A_hat_scaled @ xb; h1 = relu(dinv*(y W1) + b1)
    k_aggx<<<aggGrid, 256, 0, stream>>>(xb, rp, col, bufB);
    k_gemmP<<<gP, 256, 0, stream>>>(bufB, W1t, dinv, bb1, bufA, 128, 0);
    // conv2: @ W2 -> hs in fp8, gather in fp8
    k_gemmP<<<gP, 256, 0, stream>>>(bufA, W2t, dinv, nullptr, bufB, 256, 1);
    k_agg8<<<aggGrid, 256, 0, stream>>>((const u8*)bufB, rp, col, dinv, bb2, bufA);
    // conv3: @ W2 (reused)
    k_gemmP<<<gP, 256, 0, stream>>>(bufA, W2t, dinv, nullptr, bufB, 256, 1);
    k_agg8<<<aggGrid, 256, 0, stream>>>((const u8*)bufB, rp, col, dinv, bb2, bufA);
    // conv4: @ W3
    k_gemmP<<<gP, 256, 0, stream>>>(bufA, W3t, dinv, nullptr, bufB, 256, 1);
    k_agg8<<<aggGrid, 256, 0, stream>>>((const u8*)bufB, rp, col, dinv, bb3, bufA);
    // conv5: @ W4 (persistent-B, padded to 64 cols, bf16) + fused log_softmax
    k_gemmP64<<<256, 256, 0, stream>>>(bufA, W4t, dinv, bufB);
    k_agg5<<<aggGrid, 256, 0, stream>>>(bufB, rp, col, dinv, bb4, d_out, flags);
}

// Round 9
// 679.168 us; speedup vs baseline: 1.1219x; 1.1219x over previous
//
#include <hip/hip_runtime.h>
#include <stdint.h>
#include <math.h>

#define NN   100000
#define FIN  128
#define HIDDEN 256
#define NCLS 40
#define NE   1600000

// CSR bucketing: P node-ranges x S edge-slices
#define PRNG 8
#define RNG  12500          // NN / PRNG
#define SSL  32
#define NES  50000          // NE / SSL

typedef unsigned short u16;
typedef unsigned char u8;
typedef __attribute__((ext_vector_type(8))) short s16x8;
typedef __attribute__((ext_vector_type(4))) float f32x4;
typedef __attribute__((ext_vector_type(2))) float f32x2;

__device__ __forceinline__ float bf2f(unsigned short u) {
    union { float f; uint32_t i; } v; v.i = ((uint32_t)u) << 16; return v.f;
}
__device__ __forceinline__ unsigned short f2bf(float f) {
    union { float f; uint32_t i; } v; v.f = f;
    uint32_t r = v.i + 0x7fffu + ((v.i >> 16) & 1u);
    return (unsigned short)(r >> 16);
}
__device__ __forceinline__ u8 f2fp8(float f) {
    int r = __builtin_amdgcn_cvt_pk_fp8_f32(f, f, 0, false);
    return (u8)(r & 0xff);
}

// ---------------- dtype detection (parallel, 64 blocks) ----------------
// flags[0] != 0 => float tensors are float32 (else bf16)
// flags[2] == 0 => edge_index int64 (all odd i32 words zero), else int32
__global__ __launch_bounds__(256) void k_detect(const u16* __restrict__ x16,
                                                const int* __restrict__ ei,
                                                int* __restrict__ flags) {
    int g = blockIdx.x * 256 + threadIdx.x;      // 0..16383
    uint2 v = *(const uint2*)(x16 + (size_t)g * 4);
    int nan_cnt = 0;
    uint32_t w0 = v.x, w1 = v.y;
    if (((w0 >> 0)  & 0x7fff) >= 0x7f80) nan_cnt++;
    if (((w0 >> 16) & 0x7fff) >= 0x7f80) nan_cnt++;
    if (((w1 >> 0)  & 0x7fff) >= 0x7f80) nan_cnt++;
    if (((w1 >> 16) & 0x7fff) >= 0x7f80) nan_cnt++;
    int odd_nz = (g < 8192 && ei[2 * g + 1] != 0) ? 1 : 0;
#pragma unroll
    for (int off = 1; off < 64; off <<= 1) {
        nan_cnt += __shfl_xor(nan_cnt, off);
        odd_nz  += __shfl_xor(odd_nz, off);
    }
    if ((threadIdx.x & 63) == 0) {
        if (nan_cnt) atomicAdd(&flags[0], nan_cnt);
        if (odd_nz)  atomicAdd(&flags[2], odd_nz);
    }
}

// edge_index -> dense i32 dst/src (handles both i64 and i32 storage)
__global__ void k_compact(const int* __restrict__ ei, int* __restrict__ dst32,
                          int* __restrict__ src32, const int* __restrict__ flags) {
    int e = blockIdx.x * 256 + threadIdx.x;
    if (e < NE) {
        if (flags[2] == 0) { src32[e] = ei[2 * e]; dst32[e] = ei[2 * (NE + e)]; }
        else               { src32[e] = ei[e];     dst32[e] = ei[NE + e]; }
    }
}

// weights transpose + bias cvt + x cvt (prescaled by dinv, VECTORIZED x8), one launch
__global__ void k_trans_cvt(const void* W1, const void* W2, const void* W3, const void* W4,
                            u16* W1t, u16* W2t, u16* W3t, u16* W4t,
                            const void* b1, const void* b2, const void* b3, const void* b4,
                            u16* o1, u16* o2, u16* o3, u16* o4,
                            const void* __restrict__ x, const float* __restrict__ dinv,
                            u16* __restrict__ xb,
                            const int* __restrict__ flags) {
    int b = blockIdx.x;
    int fl = flags[0];
    int t = threadIdx.x;
    if (b >= 705) {            // x convert: 6250 blocks, 8 elems/thread
        int i8 = (b - 705) * 256 + t;
        if (i8 < NN * FIN / 8) {
            int i = i8 * 8;
            float d = dinv[i >> 7];          // 8 elems within one row (128 % 8 == 0)
            u16 r[8];
            if (fl) {
                const float* xf = (const float*)x + i;
                f32x4 v0 = *(const f32x4*)xf;
                f32x4 v1 = *(const f32x4*)(xf + 4);
#pragma unroll
                for (int k = 0; k < 4; ++k) { r[k] = f2bf(v0[k] * d); r[4 + k] = f2bf(v1[k] * d); }
            } else {
                uint4 v = *(const uint4*)((const u16*)x + i);
                uint32_t w[4] = {v.x, v.y, v.z, v.w};
#pragma unroll
                for (int k = 0; k < 4; ++k) {
                    r[2 * k]     = f2bf(bf2f((u16)(w[k] & 0xffff)) * d);
                    r[2 * k + 1] = f2bf(bf2f((u16)(w[k] >> 16)) * d);
                }
            }
            uint4 o;
            o.x = (uint32_t)r[0] | ((uint32_t)r[1] << 16);
            o.y = (uint32_t)r[2] | ((uint32_t)r[3] << 16);
            o.z = (uint32_t)r[4] | ((uint32_t)r[5] << 16);
            o.w = (uint32_t)r[6] | ((uint32_t)r[7] << 16);
            *(uint4*)(xb + i) = o;
        }
        return;
    }
    if (b == 704) {
        o1[t] = fl ? f2bf(((const float*)b1)[t]) : ((const u16*)b1)[t];
        o2[t] = fl ? f2bf(((const float*)b2)[t]) : ((const u16*)b2)[t];
        o3[t] = fl ? f2bf(((const float*)b3)[t]) : ((const u16*)b3)[t];
        if (t < 64) o4[t] = (t < NCLS) ? (fl ? f2bf(((const float*)b4)[t]) : ((const u16*)b4)[t]) : (u16)0;
        return;
    }
    const void* W; u16* Wt; int K, F, Fpad, base;
    if (b < 128)      { W = W1; Wt = W1t; K = 128; F = 256; Fpad = 256; base = 0; }
    else if (b < 384) { W = W2; Wt = W2t; K = 256; F = 256; Fpad = 256; base = 128; }
    else if (b < 640) { W = W3; Wt = W3t; K = 256; F = 256; Fpad = 256; base = 384; }
    else              { W = W4; Wt = W4t; K = 256; F = 40;  Fpad = 64;  base = 640; }
    int idx = (b - base) * 256 + t;
    if (idx >= K * Fpad) return;
    int f = idx / K, k = idx - f * K;
    u16 v = 0;
    if (f < F) {
        if (fl) v = f2bf(((const float*)W)[(size_t)k * F + f]);
        else    v = ((const u16*)W)[(size_t)k * F + f];
    }
    Wt[idx] = v;
}

// ---------------- CSR build (no device atomics; i32 inputs) ----------------

__global__ __launch_bounds__(256) void k_histb(const int* __restrict__ dst32,
                                               int* __restrict__ partial) {
    __shared__ int h[RNG];
    int p = blockIdx.x >> 5, s = blockIdx.x & 31;
    int t = threadIdx.x;
    int4 z4 = make_int4(0, 0, 0, 0);
    for (int i = t * 4; i < RNG; i += 1024) *(int4*)(h + i) = z4;
    __syncthreads();
    int base = s * NES;
    int lo = p * RNG;
    int nfull = NES & ~1023;
    for (int k = t * 4; k < nfull; k += 1024) {
        int4 d4 = *(const int4*)(dst32 + base + k);
        int a;
        a = d4.x - lo; if ((unsigned)a < RNG) atomicAdd(&h[a], 1);
        a = d4.y - lo; if ((unsigned)a < RNG) atomicAdd(&h[a], 1);
        a = d4.z - lo; if ((unsigned)a < RNG) atomicAdd(&h[a], 1);
        a = d4.w - lo; if ((unsigned)a < RNG) atomicAdd(&h[a], 1);
    }
    for (int k = nfull + t; k < NES; k += 256) {
        int a = dst32[base + k] - lo;
        if ((unsigned)a < RNG) atomicAdd(&h[a], 1);
    }
    __syncthreads();
    int* out = partial + blockIdx.x * RNG;
    for (int i = t * 4; i < RNG; i += 1024) *(int4*)(out + i) = *(const int4*)(h + i);
}

// fused: per-node degree (sum of 32 partial slices) + block-local exclusive prefix
__global__ __launch_bounds__(256) void k_scan1(const int* __restrict__ partial,
                                               int* __restrict__ cnt,
                                               int* __restrict__ out,
                                               int* __restrict__ bsum) {
    __shared__ int sh[256];
    int t = threadIdx.x;
    int base = blockIdx.x * 1024 + t * 4;
    int v0 = 0, v1 = 0, v2 = 0, v3 = 0;
    if (base < NN) {
        int p = base / RNG, il = base - p * RNG;
        const int* q = partial + (p * SSL) * RNG + il;
        int4 acc = make_int4(0, 0, 0, 0);
#pragma unroll
        for (int s = 0; s < SSL; ++s) {
            int4 w = *(const int4*)(q + s * RNG);
            acc.x += w.x; acc.y += w.y; acc.z += w.z; acc.w += w.w;
        }
        v0 = acc.x; v1 = acc.y; v2 = acc.z; v3 = acc.w;
        *(int4*)(cnt + base) = acc;
    }
    int s = v0 + v1 + v2 + v3;
    sh[t] = s;
    __syncthreads();
    for (int off = 1; off < 256; off <<= 1) {
        int x = (t >= off) ? sh[t - off] : 0;
        __syncthreads();
        sh[t] += x;
        __syncthreads();
    }
    int ex = sh[t] - s;
    if (base < NN) {
        int4 o = make_int4(ex, ex + v0, ex + v0 + v1, ex + v0 + v1 + v2);
        *(int4*)(out + base) = o;
    }
    if (t == 255) bsum[blockIdx.x] = sh[255];
}

// parallel exclusive scan of nb (<=128) block sums
__global__ void k_scan2(int* bsum, int nb) {
    __shared__ int sh[128];
    int t = threadIdx.x;
    int v = (t < nb) ? bsum[t] : 0;
    sh[t] = v;
    __syncthreads();
    for (int off = 1; off < 128; off <<= 1) {
        int x = (t >= off) ? sh[t - off] : 0;
        __syncthreads();
        sh[t] += x;
        __syncthreads();
    }
    if (t < nb) bsum[t] = sh[t] - v;
}

// finalize rp, dinv, and convert partial -> absolute slice offsets
__global__ void k_scan3o(int* __restrict__ rp, const int* __restrict__ bsum,
                         const int* __restrict__ cnt, float* __restrict__ dinv,
                         int* __restrict__ partial) {
    int i = blockIdx.x * 256 + threadIdx.x;
    if (i < NN) {
        int v = rp[i] + bsum[i >> 10];
        rp[i] = v;
        dinv[i] = rsqrtf((float)(cnt[i] + 1));
        int p = i / RNG, il = i - p * RNG;
        int* q = partial + (p * SSL) * RNG + il;
        int run = v;
#pragma unroll
        for (int s = 0; s < SSL; ++s) { int t = q[s * RNG]; q[s * RNG] = run; run += t; }
    }
    if (i == 0) rp[NN] = NE;
}

__global__ __launch_bounds__(256) void k_fillb(const int* __restrict__ dst32,
                                               const int* __restrict__ src32,
                                               const int* __restrict__ offs,
                                               int* __restrict__ col) {
    __shared__ int h[RNG];
    int p = blockIdx.x >> 5, s = blockIdx.x & 31;
    int t = threadIdx.x;
    const int* o = offs + blockIdx.x * RNG;
    for (int i = t * 4; i < RNG; i += 1024) *(int4*)(h + i) = *(const int4*)(o + i);
    __syncthreads();
    int base = s * NES;
    int lo = p * RNG;
    int nfull = NES & ~1023;
    for (int k = t * 4; k < nfull; k += 1024) {
        int4 d4 = *(const int4*)(dst32 + base + k);
        int4 s4 = *(const int4*)(src32 + base + k);
        int a;
        a = d4.x - lo; if ((unsigned)a < RNG) col[atomicAdd(&h[a], 1)] = s4.x;
        a = d4.y - lo; if ((unsigned)a < RNG) col[atomicAdd(&h[a], 1)] = s4.y;
        a = d4.z - lo; if ((unsigned)a < RNG) col[atomicAdd(&h[a], 1)] = s4.z;
        a = d4.w - lo; if ((unsigned)a < RNG) col[atomicAdd(&h[a], 1)] = s4.w;
    }
    for (int k = nfull + t; k < NES; k += 256) {
        int a = dst32[base + k] - lo;
        if ((unsigned)a < RNG) col[atomicAdd(&h[a], 1)] = src32[base + k];
    }
}

// ---------------- Persistent-B GEMM (N=256 halves): C = epi(A @ Wt^T) ----------------
// out_fp8: write hs as fp8 e4m3 (for the gather kernels); else bf16.
// LDS = Bs 64KB + As 16KB = EXACTLY 80KB -> 2 blocks/CU co-resident (160KB LDS).
// grid MUST be (256,2)=512 wg: co-residency is the latency-hiding mechanism
// (r8 measured: (128,2) -> 1 block/CU -> 9% occupancy, 68us vs ~52us).

#define GLL(g, l) __builtin_amdgcn_global_load_lds( \
    (const __attribute__((address_space(1))) unsigned int*)(g), \
    (__attribute__((address_space(3))) unsigned int*)(l), 16, 0, 0)

#define NT128 ((NN + 127) / 128)
#define NT256 ((NN + 255) / 256)

__global__ __launch_bounds__(256) void k_gemmP(const u16* __restrict__ A,
                                               const u16* __restrict__ Wt,
                                               const float* __restrict__ dinv,
                                               const u16* __restrict__ bias,
                                               u16* __restrict__ C,
                                               int K, int out_fp8) {
    __shared__ __align__(16) u16 Bs[128 * 256];   // blocked [K/32][128][32]
    __shared__ __align__(16) u16 As[2 * 128 * 32];
    int t = threadIdx.x;
    int bn = blockIdx.y;
    int w = t >> 6, lane = t & 63;
    int wm = w >> 1, wn = w & 1;
    int lrow = lane & 15, lq = lane >> 4;
    int r0 = t >> 2;
    int seg = (t & 3) * 8;

    int rounds = K >> 4;
    for (int r = 0; r < rounds; ++r) {
        int d = r * 4096 + t * 16;
        int kt = d >> 13;
        int win = d & 8191;
        int row = win >> 6;
        int sg = (win & 63) >> 1;
        GLL(Wt + (size_t)(bn * 128 + row) * K + kt * 32 + sg, Bs + (d >> 1));
    }

    int nK = K >> 5;
    bool fuse = (bias != nullptr);
    float bcol[4];
#pragma unroll
    for (int j = 0; j < 4; ++j)
        bcol[j] = fuse ? bf2f(bias[bn * 128 + wn * 64 + j * 16 + lrow]) : 0.f;

    for (int tm = blockIdx.x; tm < NT128; tm += gridDim.x) {
        int rowBase = tm * 128;
        int ar0 = rowBase + r0;       if (ar0 > NN - 1) ar0 = NN - 1;
        int ar1 = rowBase + 64 + r0;  if (ar1 > NN - 1) ar1 = NN - 1;
        const u16* a0p = A + (size_t)ar0 * K + seg;
        const u16* a1p = A + (size_t)ar1 * K + seg;
        GLL(a0p, As + t * 8);
        GLL(a1p, As + 2048 + t * 8);

        f32x4 acc[4][4] = {};
        int cur = 0;
        for (int kt = 0; kt < nK; ++kt) {
            __syncthreads();
            if (kt + 1 < nK) {
                int nxt = cur ^ 1;
                GLL(a0p + (kt + 1) * 32, As + nxt * 4096 + t * 8);
                GLL(a1p + (kt + 1) * 32, As + nxt * 4096 + 2048 + t * 8);
            }
            const u16* ab = As + cur * 4096;
            const u16* bb = Bs + kt * 4096;
            s16x8 af[4], bf[4];
#pragma unroll
            for (int i = 0; i < 4; ++i)
                af[i] = *(const s16x8*)(ab + (wm * 64 + i * 16 + lrow) * 32 + lq * 8);
#pragma unroll
            for (int j = 0; j < 4; ++j)
                bf[j] = *(const s16x8*)(bb + (wn * 64 + j * 16 + lrow) * 32 + lq * 8);
#pragma unroll
            for (int i = 0; i < 4; ++i)
#pragma unroll
                for (int j = 0; j < 4; ++j)
                    acc[i][j] = __builtin_amdgcn_mfma_f32_16x16x32_bf16(af[i], bf[j], acc[i][j], 0, 0, 0);
            cur ^= 1;
        }

        u8* C8 = (u8*)C;
#pragma unroll
        for (int i = 0; i < 4; ++i) {
#pragma unroll
            for (int rr = 0; rr < 4; ++rr) {
                int row = rowBase + wm * 64 + i * 16 + lq * 4 + rr;
                if (row < NN) {
                    float d = dinv[row];
#pragma unroll
                    for (int j = 0; j < 4; ++j) {
                        int colg = bn * 128 + wn * 64 + j * 16 + lrow;
                        float v = fuse ? fmaxf(fmaf(d, acc[i][j][rr], bcol[j]), 0.f)
                                       : acc[i][j][rr] * d;
                        if (out_fp8) C8[(size_t)row * HIDDEN + colg] = f2fp8(v);
                        else         C[(size_t)row * HIDDEN + colg] = f2bf(v);
                    }
                }
            }
        }
        __syncthreads();
    }
}

// ---------------- Persistent-B GEMM conv5: 256-row x 64-col tiles, K=256 ----------------
__global__ __launch_bounds__(256) void k_gemmP64(const u16* __restrict__ A,
                                                 const u16* __restrict__ Wt,
                                                 const float* __restrict__ dinv,
                                                 u16* __restrict__ C) {
    const int K = 256;
    __shared__ __align__(16) u16 Bs[64 * 256];
    __shared__ __align__(16) u16 As[2 * 256 * 32];
    int t = threadIdx.x;
    int w = t >> 6, lane = t & 63;
    int lrow = lane & 15, lq = lane >> 4;
    int seg = (t & 3) * 8;
    int rr0 = t >> 2;

    for (int r = 0; r < 8; ++r)
        GLL(Wt + (size_t)(t >> 2) * K + r * 32 + seg, Bs + r * 2048 + t * 8);

    for (int tm = blockIdx.x; tm < NT256; tm += gridDim.x) {
        int rowBase = tm * 256;
        const u16* ap[4];
#pragma unroll
        for (int c = 0; c < 4; ++c) {
            int ar = rowBase + c * 64 + rr0;
            if (ar > NN - 1) ar = NN - 1;
            ap[c] = A + (size_t)ar * K + seg;
        }
#pragma unroll
        for (int c = 0; c < 4; ++c) GLL(ap[c], As + c * 2048 + t * 8);

        f32x4 acc[4][4] = {};
        int cur = 0;
        for (int kt = 0; kt < 8; ++kt) {
            __syncthreads();
            if (kt + 1 < 8) {
                int nxt = cur ^ 1;
#pragma unroll
                for (int c = 0; c < 4; ++c)
                    GLL(ap[c] + (kt + 1) * 32, As + nxt * 8192 + c * 2048 + t * 8);
            }
            const u16* ab = As + cur * 8192;
            const u16* bb = Bs + kt * 2048;
            s16x8 af[4], bf[4];
#pragma unroll
            for (int i = 0; i < 4; ++i)
                af[i] = *(const s16x8*)(ab + (w * 64 + i * 16 + lrow) * 32 + lq * 8);
#pragma unroll
            for (int j = 0; j < 4; ++j)
                bf[j] = *(const s16x8*)(bb + (j * 16 + lrow) * 32 + lq * 8);
#pragma unroll
            for (int i = 0; i < 4; ++i)
#pragma unroll
                for (int j = 0; j < 4; ++j)
                    acc[i][j] = __builtin_amdgcn_mfma_f32_16x16x32_bf16(af[i], bf[j], acc[i][j], 0, 0, 0);
            cur ^= 1;
        }

#pragma unroll
        for (int i = 0; i < 4; ++i) {
#pragma unroll
            for (int rr = 0; rr < 4; ++rr) {
                int row = rowBase + w * 64 + i * 16 + lq * 4 + rr;
                if (row < NN) {
                    float d = dinv[row];
#pragma unroll
                    for (int j = 0; j < 4; ++j) {
                        int colg = j * 16 + lrow;
                        C[(size_t)row * 64 + colg] = f2bf(acc[i][j][rr] * d);
                    }
                }
            }
        }
        __syncthreads();
    }
}

// ---------------- aggregation F=256 over fp8 hs (convs 2-4) ----------------
// feature-parallel full wave: lane owns 4 fp8 features (4 B), wave walks edges.
// row/p/col are wave-uniform -> scalar loads; 8 gathers in flight (measured optimum).

__global__ __launch_bounds__(256) void k_agg8(const u8* __restrict__ hs,
                                              const int* __restrict__ rp,
                                              const int* __restrict__ col,
                                              const float* __restrict__ dinv,
                                              const u16* __restrict__ bias,
                                              u16* __restrict__ out) {
    int wq = __builtin_amdgcn_readfirstlane(threadIdx.x >> 6);
    int row = blockIdx.x * 4 + wq;
    if (row >= NN) return;
    int lane = threadIdx.x & 63;
    int fo = lane * 4;                  // feature offset (fp8: bytes == features)
    float a0 = 0.f, a1 = 0.f, a2 = 0.f, a3 = 0.f;
    auto acc_add = [&](uint32_t w) {
        f32x2 x = __builtin_amdgcn_cvt_pk_f32_fp8(w, false);
        f32x2 y = __builtin_amdgcn_cvt_pk_f32_fp8(w, true);
        a0 += x.x; a1 += x.y; a2 += y.x; a3 += y.y;
    };
    auto acc_fma = [&](uint32_t w, float m) {
        f32x2 x = __builtin_amdgcn_cvt_pk_f32_fp8(w, false);
        f32x2 y = __builtin_amdgcn_cvt_pk_f32_fp8(w, true);
        a0 = fmaf(m, x.x, a0); a1 = fmaf(m, x.y, a1);
        a2 = fmaf(m, y.x, a2); a3 = fmaf(m, y.y, a3);
    };
    acc_add(*(const uint32_t*)(hs + (size_t)row * HIDDEN + fo));   // self loop
    int p  = __builtin_amdgcn_readfirstlane(rp[row]);
    int p1 = __builtin_amdgcn_readfirstlane(rp[row + 1]);
    for (; p + 8 <= p1; p += 8) {
        uint32_t v[8];
#pragma unroll
        for (int k = 0; k < 8; ++k) {
            int c = __builtin_amdgcn_readfirstlane(col[p + k]);
            v[k] = *(const uint32_t*)(hs + (size_t)c * HIDDEN + fo);
        }
#pragma unroll
        for (int k = 0; k < 8; ++k) acc_add(v[k]);
    }
    int rem = p1 - p;                   // 0..7, wave-uniform
    if (rem) {
        uint32_t v[8];
#pragma unroll
        for (int k = 0; k < 8; ++k) {
            int idx = (k < rem) ? (p + k) : p;
            int c = __builtin_amdgcn_readfirstlane(col[idx]);
            v[k] = *(const uint32_t*)(hs + (size_t)c * HIDDEN + fo);
        }
#pragma unroll
        for (int k = 0; k < 8; ++k) acc_fma(v[k], (k < rem) ? 1.f : 0.f);
    }
    float d = dinv[row];
    uint2 bv = *(const uint2*)(bias + fo);
    float r0 = fmaxf(fmaf(d, a0, bf2f((u16)(bv.x & 0xffff))), 0.f);
    float r1 = fmaxf(fmaf(d, a1, bf2f((u16)(bv.x >> 16))), 0.f);
    float r2 = fmaxf(fmaf(d, a2, bf2f((u16)(bv.y & 0xffff))), 0.f);
    float r3 = fmaxf(fmaf(d, a3, bf2f((u16)(bv.y >> 16))), 0.f);
    uint2 o;
    o.x = (uint32_t)f2bf(r0) | ((uint32_t)f2bf(r1) << 16);
    o.y = (uint32_t)f2bf(r2) | ((uint32_t)f2bf(r3) << 16);
    *(uint2*)(out + (size_t)row * HIDDEN + fo) = o;
}

// ---------------- conv1 pre-aggregation on prescaled x (128 features, bf16) ----------------
// feature-parallel: lane owns 2 bf16 features (4 B), wave walks edges; 8 in flight.
__global__ __launch_bounds__(256) void k_aggx(const u16* __restrict__ xb,
                                              const int* __restrict__ rp,
                                              const int* __restrict__ col,
                                              u16* __restrict__ out) {
    int wq = __builtin_amdgcn_readfirstlane(threadIdx.x >> 6);
    int row = blockIdx.x * 4 + wq;
    if (row >= NN) return;
    int lane = threadIdx.x & 63;
    int fo = lane * 2;                  // u16 index: 2 bf16 per lane
    float a0 = 0.f, a1 = 0.f;
    auto acc_add = [&](uint32_t w) {
        a0 += bf2f((u16)(w & 0xffff));
        a1 += bf2f((u16)(w >> 16));
    };
    auto acc_fma = [&](uint32_t w, float m) {
        a0 = fmaf(m, bf2f((u16)(w & 0xffff)), a0);
        a1 = fmaf(m, bf2f((u16)(w >> 16)), a1);
    };
    acc_add(*(const uint32_t*)(xb + (size_t)row * FIN + fo));      // self loop
    int p  = __builtin_amdgcn_readfirstlane(rp[row]);
    int p1 = __builtin_amdgcn_readfirstlane(rp[row + 1]);
    for (; p + 8 <= p1; p += 8) {
        uint32_t v[8];
#pragma unroll
        for (int k = 0; k < 8; ++k) {
            int c = __builtin_amdgcn_readfirstlane(col[p + k]);
            v[k] = *(const uint32_t*)(xb + (size_t)c * FIN + fo);
        }
#pragma unroll
        for (int k = 0; k < 8; ++k) acc_add(v[k]);
    }
    int rem = p1 - p;
    if (rem) {
        uint32_t v[8];
#pragma unroll
        for (int k = 0; k < 8; ++k) {
            int idx = (k < rem) ? (p + k) : p;
            int c = __builtin_amdgcn_readfirstlane(col[idx]);
            v[k] = *(const uint32_t*)(xb + (size_t)c * FIN + fo);
        }
#pragma unroll
        for (int k = 0; k < 8; ++k) acc_fma(v[k], (k < rem) ? 1.f : 0.f);
    }
    uint32_t o = (uint32_t)f2bf(a0) | ((uint32_t)f2bf(a1) << 16);
    *(uint32_t*)(out + (size_t)row * FIN + fo) = o;
}

// ---------------- last layer: hs padded to 64 cols (bf16); agg + bias + log_softmax ----------------
// feature-parallel: lane owns 1 class (2 B), wave walks edges; softmax across lanes.
__global__ __launch_bounds__(256) void k_agg5(const u16* __restrict__ hs,
                                              const int* __restrict__ rp,
                                              const int* __restrict__ col,
                                              const float* __restrict__ dinv,
                                              const u16* __restrict__ bias,
                                              void* __restrict__ out,
                                              const int* __restrict__ flags) {
    int wq = __builtin_amdgcn_readfirstlane(threadIdx.x >> 6);
    int row = blockIdx.x * 4 + wq;
    if (row >= NN) return;
    int lane = threadIdx.x & 63;
    float a = bf2f(hs[(size_t)row * 64 + lane]);                   // self loop
    int p  = __builtin_amdgcn_readfirstlane(rp[row]);
    int p1 = __builtin_amdgcn_readfirstlane(rp[row + 1]);
    for (; p + 8 <= p1; p += 8) {
        u16 v[8];
#pragma unroll
        for (int k = 0; k < 8; ++k) {
            int c = __builtin_amdgcn_readfirstlane(col[p + k]);
            v[k] = hs[(size_t)c * 64 + lane];
        }
#pragma unroll
        for (int k = 0; k < 8; ++k) a += bf2f(v[k]);
    }
    int rem = p1 - p;
    if (rem) {
        u16 v[8];
#pragma unroll
        for (int k = 0; k < 8; ++k) {
            int idx = (k < rem) ? (p + k) : p;
            int c = __builtin_amdgcn_readfirstlane(col[idx]);
            v[k] = hs[(size_t)c * 64 + lane];
        }
#pragma unroll
        for (int k = 0; k < 8; ++k)
            a = fmaf((k < rem) ? 1.f : 0.f, bf2f(v[k]), a);
    }
    bool act = lane < NCLS;
    float d = dinv[row];
    float l = act ? fmaf(d, a, bf2f(bias[lane])) : -1e30f;
    float m = l;
#pragma unroll
    for (int off = 32; off > 0; off >>= 1) m = fmaxf(m, __shfl_xor(m, off));
    float e = act ? __expf(l - m) : 0.f;
#pragma unroll
    for (int off = 32; off > 0; off >>= 1) e += __shfl_xor(e, off);
    if (act) {
        float r = l - m - __logf(e);
        if (flags[0]) ((float*)out)[(size_t)row * NCLS + lane] = r;
        else          ((u16*)out)[(size_t)row * NCLS + lane] = f2bf(r);
    }
}

// ---------------- launch ----------------

extern "C" void kernel_launch(void* const* d_in, const int* in_sizes, int n_in,
                              void* d_out, int out_size, void* d_ws, size_t ws_size,
                              hipStream_t stream) {
    const void* x  = d_in[0];
    const int* ei  = (const int*)d_in[1];
    const void* W1 = d_in[2];
    const void* b1 = d_in[3];
    const void* W2 = d_in[4];
    const void* b2 = d_in[5];
    const void* W3 = d_in[6];
    const void* b3 = d_in[7];
    const void* W4 = d_in[8];
    const void* b4 = d_in[9];

    char* p = (char*)d_ws;
    auto alloc = [&](size_t b) -> char* {
        char* r = p;
        p += (b + 255) & ~(size_t)255;
        return r;
    };
    int*   flags = (int*)alloc(256);
    int*   cnt  = (int*)alloc((size_t)NN * 4);
    float* dinv = (float*)alloc((size_t)NN * 4);
    int*   rp   = (int*)alloc((size_t)(NN + 1) * 4);
    int*   col  = (int*)alloc((size_t)NE * 4);
    int*   bsum = (int*)alloc(4096);
    u16* xb  = (u16*)alloc((size_t)NN * FIN * 2);
    u16* W1t = (u16*)alloc((size_t)256 * 128 * 2);
    u16* W2t = (u16*)alloc((size_t)256 * 256 * 2);
    u16* W3t = (u16*)alloc((size_t)256 * 256 * 2);
    u16* W4t = (u16*)alloc((size_t)64 * 256 * 2);
    u16* bb1 = (u16*)alloc(512);
    u16* bb2 = (u16*)alloc(512);
    u16* bb3 = (u16*)alloc(512);
    u16* bb4 = (u16*)alloc(128);
    u16* bufA = (u16*)alloc((size_t)NN * HIDDEN * 2);
    u16* bufB = (u16*)alloc((size_t)NN * HIDDEN * 2);

    // CSR-build scratch aliased into conv buffers (dead before conv use)
    int* dst32   = (int*)bufA;                    // 6.4 MB
    int* src32   = dst32 + NE;                    // 6.4 MB
    int* partial = (int*)bufB;                    // 12.8 MB

    hipMemsetAsync(flags, 0, 16, stream);
    k_detect<<<64, 256, 0, stream>>>((const u16*)x, ei, flags);
    k_compact<<<(NE + 255) / 256, 256, 0, stream>>>(ei, dst32, src32, flags);

    // CSR build (atomic-free at device scope, i32 streams)
    k_histb<<<PRNG * SSL, 256, 0, stream>>>(dst32, partial);
    k_scan1<<<(NN + 1023) / 1024, 256, 0, stream>>>(partial, cnt, rp, bsum);
    k_scan2<<<1, 128, 0, stream>>>(bsum, (NN + 1023) / 1024);
    k_scan3o<<<(NN + 255) / 256, 256, 0, stream>>>(rp, bsum, cnt, dinv, partial);
    k_fillb<<<PRNG * SSL, 256, 0, stream>>>(dst32, src32, partial, col);

    // weights/bias transpose + x convert (prescaled by dinv, vectorized), one launch
    k_trans_cvt<<<705 + (NN * FIN / 8 + 255) / 256, 256, 0, stream>>>(
        W1, W2, W3, W4, W1t, W2t, W3t, W4t,
        b1, b2, b3, b4, bb1, bb2, bb3, bb4, x, dinv, xb, flags);

    dim3 gP(256, 2);    // 512 wg = 2 blocks/CU CO-RESIDENT (80KB LDS each) — do not shrink
    dim3 aggGrid((NN + 3) / 4);

    // conv1 (aggregate-then-transform): y = A_hat_scaled @ xb; h1 = relu(dinv*(y W1) + b1)
    k_aggx<<<aggGrid, 256, 0, stream>>>(xb, rp, col, bufB);
    k_gemmP<<<gP, 256, 0, stream>>>(bufB, W1t, dinv, bb1, bufA, 128, 0);
    // conv2: @ W2 -> hs in fp8, gather in fp8
    k_gemmP<<<gP, 256, 0, stream>>>(bufA, W2t, dinv, nullptr, bufB, 256, 1);
    k_agg8<<<aggGrid, 256, 0, stream>>>((const u8*)bufB, rp, col, dinv, bb2, bufA);
    // conv3: @ W2 (reused)
    k_gemmP<<<gP, 256, 0, stream>>>(bufA, W2t, dinv, nullptr, bufB, 256, 1);
    k_agg8<<<aggGrid, 256, 0, stream>>>((const u8*)bufB, rp, col, dinv, bb2, bufA);
    // conv4: @ W3
    k_gemmP<<<gP, 256, 0, stream>>>(bufA, W3t, dinv, nullptr, bufB, 256, 1);
    k_agg8<<<aggGrid, 256, 0, stream>>>((const u8*)bufB, rp, col, dinv, bb3, bufA);
    // conv5: @ W4 (persistent-B, padded to 64 cols, bf16) + fused log_softmax
    k_gemmP64<<<256, 256, 0, stream>>>(bufA, W4t, dinv, bufB);
    k_agg5<<<aggGrid, 256, 0, stream>>>(bufB, rp, col, dinv, bb4, d_out, flags);
}

// Round 10
// 671.814 us; speedup vs baseline: 1.1342x; 1.0109x over previous
//
#include <hip/hip_runtime.h>
#include <stdint.h>
#include <math.h>

#define NN   100000
#define FIN  128
#define HIDDEN 256
#define NCLS 40
#define NE   1600000

// CSR bucketing: P node-ranges x S edge-slices
#define PRNG 8
#define RNG  12500          // NN / PRNG
#define SSL  32
#define NES  50000          // NE / SSL

typedef unsigned short u16;
typedef unsigned char u8;
typedef __attribute__((ext_vector_type(8))) short s16x8;
typedef __attribute__((ext_vector_type(4))) float f32x4;
typedef __attribute__((ext_vector_type(2))) float f32x2;

__device__ __forceinline__ float bf2f(unsigned short u) {
    union { float f; uint32_t i; } v; v.i = ((uint32_t)u) << 16; return v.f;
}
__device__ __forceinline__ unsigned short f2bf(float f) {
    union { float f; uint32_t i; } v; v.f = f;
    uint32_t r = v.i + 0x7fffu + ((v.i >> 16) & 1u);
    return (unsigned short)(r >> 16);
}
__device__ __forceinline__ u8 f2fp8(float f) {
    int r = __builtin_amdgcn_cvt_pk_fp8_f32(f, f, 0, false);
    return (u8)(r & 0xff);
}

// LDS anti-bank-conflict swizzle for the [row][4 x 8u16] tiles (64B row stride):
// slot' = slot ^ S(row), S(row) = row[1] | (row[3]<<1).
// Staging threads (slot = t&3, row ~ t>>2): F(t) = t[3] | (t[5]<<1).
// Fragment reads (row bits 1,3 == lrow bits 1,3): G(lrow) = lrow[1] | (lrow[3]<<1).
// Source permutation == read permutation (involution) -> bijective per row; GLL dest stays linear.
#define SWZ_T(t)  ((((t) >> 3) & 1) | ((((t) >> 5) & 1) << 1))
#define SWZ_L(lr) ((((lr) >> 1) & 1) | ((((lr) >> 3) & 1) << 1))

// ---------------- dtype detection (parallel, 64 blocks) ----------------
// flags[0] != 0 => float tensors are float32 (else bf16)
// flags[2] == 0 => edge_index int64 (all odd i32 words zero), else int32
__global__ __launch_bounds__(256) void k_detect(const u16* __restrict__ x16,
                                                const int* __restrict__ ei,
                                                int* __restrict__ flags) {
    int g = blockIdx.x * 256 + threadIdx.x;      // 0..16383
    uint2 v = *(const uint2*)(x16 + (size_t)g * 4);
    int nan_cnt = 0;
    uint32_t w0 = v.x, w1 = v.y;
    if (((w0 >> 0)  & 0x7fff) >= 0x7f80) nan_cnt++;
    if (((w0 >> 16) & 0x7fff) >= 0x7f80) nan_cnt++;
    if (((w1 >> 0)  & 0x7fff) >= 0x7f80) nan_cnt++;
    if (((w1 >> 16) & 0x7fff) >= 0x7f80) nan_cnt++;
    int odd_nz = (g < 8192 && ei[2 * g + 1] != 0) ? 1 : 0;
#pragma unroll
    for (int off = 1; off < 64; off <<= 1) {
        nan_cnt += __shfl_xor(nan_cnt, off);
        odd_nz  += __shfl_xor(odd_nz, off);
    }
    if ((threadIdx.x & 63) == 0) {
        if (nan_cnt) atomicAdd(&flags[0], nan_cnt);
        if (odd_nz)  atomicAdd(&flags[2], odd_nz);
    }
}

// edge_index -> dense i32 dst/src (handles both i64 and i32 storage)
__global__ void k_compact(const int* __restrict__ ei, int* __restrict__ dst32,
                          int* __restrict__ src32, const int* __restrict__ flags) {
    int e = blockIdx.x * 256 + threadIdx.x;
    if (e < NE) {
        if (flags[2] == 0) { src32[e] = ei[2 * e]; dst32[e] = ei[2 * (NE + e)]; }
        else               { src32[e] = ei[e];     dst32[e] = ei[NE + e]; }
    }
}

// weights transpose + bias cvt + x cvt (prescaled by dinv, VECTORIZED x8), one launch
__global__ void k_trans_cvt(const void* W1, const void* W2, const void* W3, const void* W4,
                            u16* W1t, u16* W2t, u16* W3t, u16* W4t,
                            const void* b1, const void* b2, const void* b3, const void* b4,
                            u16* o1, u16* o2, u16* o3, u16* o4,
                            const void* __restrict__ x, const float* __restrict__ dinv,
                            u16* __restrict__ xb,
                            const int* __restrict__ flags) {
    int b = blockIdx.x;
    int fl = flags[0];
    int t = threadIdx.x;
    if (b >= 705) {            // x convert: 6250 blocks, 8 elems/thread
        int i8 = (b - 705) * 256 + t;
        if (i8 < NN * FIN / 8) {
            int i = i8 * 8;
            float d = dinv[i >> 7];          // 8 elems within one row (128 % 8 == 0)
            u16 r[8];
            if (fl) {
                const float* xf = (const float*)x + i;
                f32x4 v0 = *(const f32x4*)xf;
                f32x4 v1 = *(const f32x4*)(xf + 4);
#pragma unroll
                for (int k = 0; k < 4; ++k) { r[k] = f2bf(v0[k] * d); r[4 + k] = f2bf(v1[k] * d); }
            } else {
                uint4 v = *(const uint4*)((const u16*)x + i);
                uint32_t w[4] = {v.x, v.y, v.z, v.w};
#pragma unroll
                for (int k = 0; k < 4; ++k) {
                    r[2 * k]     = f2bf(bf2f((u16)(w[k] & 0xffff)) * d);
                    r[2 * k + 1] = f2bf(bf2f((u16)(w[k] >> 16)) * d);
                }
            }
            uint4 o;
            o.x = (uint32_t)r[0] | ((uint32_t)r[1] << 16);
            o.y = (uint32_t)r[2] | ((uint32_t)r[3] << 16);
            o.z = (uint32_t)r[4] | ((uint32_t)r[5] << 16);
            o.w = (uint32_t)r[6] | ((uint32_t)r[7] << 16);
            *(uint4*)(xb + i) = o;
        }
        return;
    }
    if (b == 704) {
        o1[t] = fl ? f2bf(((const float*)b1)[t]) : ((const u16*)b1)[t];
        o2[t] = fl ? f2bf(((const float*)b2)[t]) : ((const u16*)b2)[t];
        o3[t] = fl ? f2bf(((const float*)b3)[t]) : ((const u16*)b3)[t];
        if (t < 64) o4[t] = (t < NCLS) ? (fl ? f2bf(((const float*)b4)[t]) : ((const u16*)b4)[t]) : (u16)0;
        return;
    }
    const void* W; u16* Wt; int K, F, Fpad, base;
    if (b < 128)      { W = W1; Wt = W1t; K = 128; F = 256; Fpad = 256; base = 0; }
    else if (b < 384) { W = W2; Wt = W2t; K = 256; F = 256; Fpad = 256; base = 128; }
    else if (b < 640) { W = W3; Wt = W3t; K = 256; F = 256; Fpad = 256; base = 384; }
    else              { W = W4; Wt = W4t; K = 256; F = 40;  Fpad = 64;  base = 640; }
    int idx = (b - base) * 256 + t;
    if (idx >= K * Fpad) return;
    int f = idx / K, k = idx - f * K;
    u16 v = 0;
    if (f < F) {
        if (fl) v = f2bf(((const float*)W)[(size_t)k * F + f]);
        else    v = ((const u16*)W)[(size_t)k * F + f];
    }
    Wt[idx] = v;
}

// ---------------- CSR build (no device atomics; i32 inputs) ----------------

__global__ __launch_bounds__(256) void k_histb(const int* __restrict__ dst32,
                                               int* __restrict__ partial) {
    __shared__ int h[RNG];
    int p = blockIdx.x >> 5, s = blockIdx.x & 31;
    int t = threadIdx.x;
    int4 z4 = make_int4(0, 0, 0, 0);
    for (int i = t * 4; i < RNG; i += 1024) *(int4*)(h + i) = z4;
    __syncthreads();
    int base = s * NES;
    int lo = p * RNG;
    int nfull = NES & ~1023;
    for (int k = t * 4; k < nfull; k += 1024) {
        int4 d4 = *(const int4*)(dst32 + base + k);
        int a;
        a = d4.x - lo; if ((unsigned)a < RNG) atomicAdd(&h[a], 1);
        a = d4.y - lo; if ((unsigned)a < RNG) atomicAdd(&h[a], 1);
        a = d4.z - lo; if ((unsigned)a < RNG) atomicAdd(&h[a], 1);
        a = d4.w - lo; if ((unsigned)a < RNG) atomicAdd(&h[a], 1);
    }
    for (int k = nfull + t; k < NES; k += 256) {
        int a = dst32[base + k] - lo;
        if ((unsigned)a < RNG) atomicAdd(&h[a], 1);
    }
    __syncthreads();
    int* out = partial + blockIdx.x * RNG;
    for (int i = t * 4; i < RNG; i += 1024) *(int4*)(out + i) = *(const int4*)(h + i);
}

// fused: per-node degree (sum of 32 partial slices) + block-local exclusive prefix
__global__ __launch_bounds__(256) void k_scan1(const int* __restrict__ partial,
                                               int* __restrict__ cnt,
                                               int* __restrict__ out,
                                               int* __restrict__ bsum) {
    __shared__ int sh[256];
    int t = threadIdx.x;
    int base = blockIdx.x * 1024 + t * 4;
    int v0 = 0, v1 = 0, v2 = 0, v3 = 0;
    if (base < NN) {
        int p = base / RNG, il = base - p * RNG;
        const int* q = partial + (p * SSL) * RNG + il;
        int4 acc = make_int4(0, 0, 0, 0);
#pragma unroll
        for (int s = 0; s < SSL; ++s) {
            int4 w = *(const int4*)(q + s * RNG);
            acc.x += w.x; acc.y += w.y; acc.z += w.z; acc.w += w.w;
        }
        v0 = acc.x; v1 = acc.y; v2 = acc.z; v3 = acc.w;
        *(int4*)(cnt + base) = acc;
    }
    int s = v0 + v1 + v2 + v3;
    sh[t] = s;
    __syncthreads();
    for (int off = 1; off < 256; off <<= 1) {
        int x = (t >= off) ? sh[t - off] : 0;
        __syncthreads();
        sh[t] += x;
        __syncthreads();
    }
    int ex = sh[t] - s;
    if (base < NN) {
        int4 o = make_int4(ex, ex + v0, ex + v0 + v1, ex + v0 + v1 + v2);
        *(int4*)(out + base) = o;
    }
    if (t == 255) bsum[blockIdx.x] = sh[255];
}

// parallel exclusive scan of nb (<=128) block sums
__global__ void k_scan2(int* bsum, int nb) {
    __shared__ int sh[128];
    int t = threadIdx.x;
    int v = (t < nb) ? bsum[t] : 0;
    sh[t] = v;
    __syncthreads();
    for (int off = 1; off < 128; off <<= 1) {
        int x = (t >= off) ? sh[t - off] : 0;
        __syncthreads();
        sh[t] += x;
        __syncthreads();
    }
    if (t < nb) bsum[t] = sh[t] - v;
}

// finalize rp, dinv, and convert partial -> absolute slice offsets
__global__ void k_scan3o(int* __restrict__ rp, const int* __restrict__ bsum,
                         const int* __restrict__ cnt, float* __restrict__ dinv,
                         int* __restrict__ partial) {
    int i = blockIdx.x * 256 + threadIdx.x;
    if (i < NN) {
        int v = rp[i] + bsum[i >> 10];
        rp[i] = v;
        dinv[i] = rsqrtf((float)(cnt[i] + 1));
        int p = i / RNG, il = i - p * RNG;
        int* q = partial + (p * SSL) * RNG + il;
        int run = v;
#pragma unroll
        for (int s = 0; s < SSL; ++s) { int t = q[s * RNG]; q[s * RNG] = run; run += t; }
    }
    if (i == 0) rp[NN] = NE;
}

__global__ __launch_bounds__(256) void k_fillb(const int* __restrict__ dst32,
                                               const int* __restrict__ src32,
                                               const int* __restrict__ offs,
                                               int* __restrict__ col) {
    __shared__ int h[RNG];
    int p = blockIdx.x >> 5, s = blockIdx.x & 31;
    int t = threadIdx.x;
    const int* o = offs + blockIdx.x * RNG;
    for (int i = t * 4; i < RNG; i += 1024) *(int4*)(h + i) = *(const int4*)(o + i);
    __syncthreads();
    int base = s * NES;
    int lo = p * RNG;
    int nfull = NES & ~1023;
    for (int k = t * 4; k < nfull; k += 1024) {
        int4 d4 = *(const int4*)(dst32 + base + k);
        int4 s4 = *(const int4*)(src32 + base + k);
        int a;
        a = d4.x - lo; if ((unsigned)a < RNG) col[atomicAdd(&h[a], 1)] = s4.x;
        a = d4.y - lo; if ((unsigned)a < RNG) col[atomicAdd(&h[a], 1)] = s4.y;
        a = d4.z - lo; if ((unsigned)a < RNG) col[atomicAdd(&h[a], 1)] = s4.z;
        a = d4.w - lo; if ((unsigned)a < RNG) col[atomicAdd(&h[a], 1)] = s4.w;
    }
    for (int k = nfull + t; k < NES; k += 256) {
        int a = dst32[base + k] - lo;
        if ((unsigned)a < RNG) col[atomicAdd(&h[a], 1)] = src32[base + k];
    }
}

// ---------------- Persistent-B GEMM (N=256 halves): C = epi(A @ Wt^T) ----------------
// out_fp8: write hs as fp8 e4m3 (for the gather kernels); else bf16.
// LDS = Bs 64KB + As 16KB = EXACTLY 80KB -> 2 blocks/CU co-resident (160KB LDS).
// grid MUST be (256,2)=512 wg: co-residency is the latency-hiding mechanism
// (r8 measured: (128,2) -> 1 block/CU -> 9% occupancy, 68us vs ~52us).
// LDS slot-swizzle (SWZ_*) kills the 8-way bank conflict on ds_read_b128
// (r8 measured 1.6M SQ_LDS_BANK_CONFLICT/dispatch with linear slots).

#define GLL(g, l) __builtin_amdgcn_global_load_lds( \
    (const __attribute__((address_space(1))) unsigned int*)(g), \
    (__attribute__((address_space(3))) unsigned int*)(l), 16, 0, 0)

#define NT128 ((NN + 127) / 128)
#define NT256 ((NN + 255) / 256)

__global__ __launch_bounds__(256) void k_gemmP(const u16* __restrict__ A,
                                               const u16* __restrict__ Wt,
                                               const float* __restrict__ dinv,
                                               const u16* __restrict__ bias,
                                               u16* __restrict__ C,
                                               int K, int out_fp8) {
    __shared__ __align__(16) u16 Bs[128 * 256];   // blocked [K/32][128][4 slots x 8]
    __shared__ __align__(16) u16 As[2 * 128 * 32];
    int t = threadIdx.x;
    int bn = blockIdx.y;
    int w = t >> 6, lane = t & 63;
    int wm = w >> 1, wn = w & 1;
    int lrow = lane & 15, lq = lane >> 4;
    int r0 = t >> 2;
    int seg = ((t & 3) ^ SWZ_T(t)) * 8;           // pre-swizzled global source segment
    int lqs = (lq ^ SWZ_L(lrow)) * 8;             // swizzled LDS read slot (per-lane const)

    int rounds = K >> 4;
    for (int r = 0; r < rounds; ++r) {
        int d = r * 4096 + t * 16;
        int kt = d >> 13;
        int win = d & 8191;
        int row = win >> 6;
        int slot = (win >> 4) & 3;
        int sg = (slot ^ SWZ_T(t)) * 8;           // row bits 1,3 == t bits 3,5
        GLL(Wt + (size_t)(bn * 128 + row) * K + kt * 32 + sg, Bs + (d >> 1));
    }

    int nK = K >> 5;
    bool fuse = (bias != nullptr);
    float bcol[4];
#pragma unroll
    for (int j = 0; j < 4; ++j)
        bcol[j] = fuse ? bf2f(bias[bn * 128 + wn * 64 + j * 16 + lrow]) : 0.f;

    for (int tm = blockIdx.x; tm < NT128; tm += gridDim.x) {
        int rowBase = tm * 128;
        int ar0 = rowBase + r0;       if (ar0 > NN - 1) ar0 = NN - 1;
        int ar1 = rowBase + 64 + r0;  if (ar1 > NN - 1) ar1 = NN - 1;
        const u16* a0p = A + (size_t)ar0 * K + seg;
        const u16* a1p = A + (size_t)ar1 * K + seg;
        GLL(a0p, As + t * 8);
        GLL(a1p, As + 2048 + t * 8);

        f32x4 acc[4][4] = {};
        int cur = 0;
        for (int kt = 0; kt < nK; ++kt) {
            __syncthreads();
            if (kt + 1 < nK) {
                int nxt = cur ^ 1;
                GLL(a0p + (kt + 1) * 32, As + nxt * 4096 + t * 8);
                GLL(a1p + (kt + 1) * 32, As + nxt * 4096 + 2048 + t * 8);
            }
            const u16* ab = As + cur * 4096;
            const u16* bb = Bs + kt * 4096;
            s16x8 af[4], bf[4];
#pragma unroll
            for (int i = 0; i < 4; ++i)
                af[i] = *(const s16x8*)(ab + (wm * 64 + i * 16 + lrow) * 32 + lqs);
#pragma unroll
            for (int j = 0; j < 4; ++j)
                bf[j] = *(const s16x8*)(bb + (wn * 64 + j * 16 + lrow) * 32 + lqs);
#pragma unroll
            for (int i = 0; i < 4; ++i)
#pragma unroll
                for (int j = 0; j < 4; ++j)
                    acc[i][j] = __builtin_amdgcn_mfma_f32_16x16x32_bf16(af[i], bf[j], acc[i][j], 0, 0, 0);
            cur ^= 1;
        }

        u8* C8 = (u8*)C;
#pragma unroll
        for (int i = 0; i < 4; ++i) {
#pragma unroll
            for (int rr = 0; rr < 4; ++rr) {
                int row = rowBase + wm * 64 + i * 16 + lq * 4 + rr;
                if (row < NN) {
                    float d = dinv[row];
#pragma unroll
                    for (int j = 0; j < 4; ++j) {
                        int colg = bn * 128 + wn * 64 + j * 16 + lrow;
                        float v = fuse ? fmaxf(fmaf(d, acc[i][j][rr], bcol[j]), 0.f)
                                       : acc[i][j][rr] * d;
                        if (out_fp8) C8[(size_t)row * HIDDEN + colg] = f2fp8(v);
                        else         C[(size_t)row * HIDDEN + colg] = f2bf(v);
                    }
                }
            }
        }
        __syncthreads();
    }
}

// ---------------- Persistent-B GEMM conv5: 256-row x 64-col tiles, K=256 ----------------
__global__ __launch_bounds__(256) void k_gemmP64(const u16* __restrict__ A,
                                                 const u16* __restrict__ Wt,
                                                 const float* __restrict__ dinv,
                                                 u16* __restrict__ C) {
    const int K = 256;
    __shared__ __align__(16) u16 Bs[64 * 256];
    __shared__ __align__(16) u16 As[2 * 256 * 32];
    int t = threadIdx.x;
    int w = t >> 6, lane = t & 63;
    int lrow = lane & 15, lq = lane >> 4;
    int seg = ((t & 3) ^ SWZ_T(t)) * 8;
    int lqs = (lq ^ SWZ_L(lrow)) * 8;
    int rr0 = t >> 2;

    for (int r = 0; r < 8; ++r)
        GLL(Wt + (size_t)(t >> 2) * K + r * 32 + seg, Bs + r * 2048 + t * 8);

    for (int tm = blockIdx.x; tm < NT256; tm += gridDim.x) {
        int rowBase = tm * 256;
        const u16* ap[4];
#pragma unroll
        for (int c = 0; c < 4; ++c) {
            int ar = rowBase + c * 64 + rr0;
            if (ar > NN - 1) ar = NN - 1;
            ap[c] = A + (size_t)ar * K + seg;
        }
#pragma unroll
        for (int c = 0; c < 4; ++c) GLL(ap[c], As + c * 2048 + t * 8);

        f32x4 acc[4][4] = {};
        int cur = 0;
        for (int kt = 0; kt < 8; ++kt) {
            __syncthreads();
            if (kt + 1 < 8) {
                int nxt = cur ^ 1;
#pragma unroll
                for (int c = 0; c < 4; ++c)
                    GLL(ap[c] + (kt + 1) * 32, As + nxt * 8192 + c * 2048 + t * 8);
            }
            const u16* ab = As + cur * 8192;
            const u16* bb = Bs + kt * 2048;
            s16x8 af[4], bf[4];
#pragma unroll
            for (int i = 0; i < 4; ++i)
                af[i] = *(const s16x8*)(ab + (w * 64 + i * 16 + lrow) * 32 + lqs);
#pragma unroll
            for (int j = 0; j < 4; ++j)
                bf[j] = *(const s16x8*)(bb + (j * 16 + lrow) * 32 + lqs);
#pragma unroll
            for (int i = 0; i < 4; ++i)
#pragma unroll
                for (int j = 0; j < 4; ++j)
                    acc[i][j] = __builtin_amdgcn_mfma_f32_16x16x32_bf16(af[i], bf[j], acc[i][j], 0, 0, 0);
            cur ^= 1;
        }

#pragma unroll
        for (int i = 0; i < 4; ++i) {
#pragma unroll
            for (int rr = 0; rr < 4; ++rr) {
                int row = rowBase + w * 64 + i * 16 + lq * 4 + rr;
                if (row < NN) {
                    float d = dinv[row];
#pragma unroll
                    for (int j = 0; j < 4; ++j) {
                        int colg = j * 16 + lrow;
                        C[(size_t)row * 64 + colg] = f2bf(acc[i][j][rr] * d);
                    }
                }
            }
        }
        __syncthreads();
    }
}

// ---------------- aggregation F=256 over fp8 hs (convs 2-4) ----------------
// feature-parallel full wave: lane owns 4 fp8 features (4 B), wave walks edges.
// row/p/col are wave-uniform -> scalar loads; 8 gathers in flight (measured optimum).

__global__ __launch_bounds__(256) void k_agg8(const u8* __restrict__ hs,
                                              const int* __restrict__ rp,
                                              const int* __restrict__ col,
                                              const float* __restrict__ dinv,
                                              const u16* __restrict__ bias,
                                              u16* __restrict__ out) {
    int wq = __builtin_amdgcn_readfirstlane(threadIdx.x >> 6);
    int row = blockIdx.x * 4 + wq;
    if (row >= NN) return;
    int lane = threadIdx.x & 63;
    int fo = lane * 4;                  // feature offset (fp8: bytes == features)
    float a0 = 0.f, a1 = 0.f, a2 = 0.f, a3 = 0.f;
    auto acc_add = [&](uint32_t w) {
        f32x2 x = __builtin_amdgcn_cvt_pk_f32_fp8(w, false);
        f32x2 y = __builtin_amdgcn_cvt_pk_f32_fp8(w, true);
        a0 += x.x; a1 += x.y; a2 += y.x; a3 += y.y;
    };
    auto acc_fma = [&](uint32_t w, float m) {
        f32x2 x = __builtin_amdgcn_cvt_pk_f32_fp8(w, false);
        f32x2 y = __builtin_amdgcn_cvt_pk_f32_fp8(w, true);
        a0 = fmaf(m, x.x, a0); a1 = fmaf(m, x.y, a1);
        a2 = fmaf(m, y.x, a2); a3 = fmaf(m, y.y, a3);
    };
    acc_add(*(const uint32_t*)(hs + (size_t)row * HIDDEN + fo));   // self loop
    int p  = __builtin_amdgcn_readfirstlane(rp[row]);
    int p1 = __builtin_amdgcn_readfirstlane(rp[row + 1]);
    for (; p + 8 <= p1; p += 8) {
        uint32_t v[8];
#pragma unroll
        for (int k = 0; k < 8; ++k) {
            int c = __builtin_amdgcn_readfirstlane(col[p + k]);
            v[k] = *(const uint32_t*)(hs + (size_t)c * HIDDEN + fo);
        }
#pragma unroll
        for (int k = 0; k < 8; ++k) acc_add(v[k]);
    }
    int rem = p1 - p;                   // 0..7, wave-uniform
    if (rem) {
        uint32_t v[8];
#pragma unroll
        for (int k = 0; k < 8; ++k) {
            int idx = (k < rem) ? (p + k) : p;
            int c = __builtin_amdgcn_readfirstlane(col[idx]);
            v[k] = *(const uint32_t*)(hs + (size_t)c * HIDDEN + fo);
        }
#pragma unroll
        for (int k = 0; k < 8; ++k) acc_fma(v[k], (k < rem) ? 1.f : 0.f);
    }
    float d = dinv[row];
    uint2 bv = *(const uint2*)(bias + fo);
    float r0 = fmaxf(fmaf(d, a0, bf2f((u16)(bv.x & 0xffff))), 0.f);
    float r1 = fmaxf(fmaf(d, a1, bf2f((u16)(bv.x >> 16))), 0.f);
    float r2 = fmaxf(fmaf(d, a2, bf2f((u16)(bv.y & 0xffff))), 0.f);
    float r3 = fmaxf(fmaf(d, a3, bf2f((u16)(bv.y >> 16))), 0.f);
    uint2 o;
    o.x = (uint32_t)f2bf(r0) | ((uint32_t)f2bf(r1) << 16);
    o.y = (uint32_t)f2bf(r2) | ((uint32_t)f2bf(r3) << 16);
    *(uint2*)(out + (size_t)row * HIDDEN + fo) = o;
}

// ---------------- conv1 pre-aggregation on prescaled x (128 features, bf16) ----------------
// feature-parallel: lane owns 2 bf16 features (4 B), wave walks edges; 8 in flight.
__global__ __launch_bounds__(256) void k_aggx(const u16* __restrict__ xb,
                                              const int* __restrict__ rp,
                                              const int* __restrict__ col,
                                              u16* __restrict__ out) {
    int wq = __builtin_amdgcn_readfirstlane(threadIdx.x >> 6);
    int row = blockIdx.x * 4 + wq;
    if (row >= NN) return;
    int lane = threadIdx.x & 63;
    int fo = lane * 2;                  // u16 index: 2 bf16 per lane
    float a0 = 0.f, a1 = 0.f;
    auto acc_add = [&](uint32_t w) {
        a0 += bf2f((u16)(w & 0xffff));
        a1 += bf2f((u16)(w >> 16));
    };
    auto acc_fma = [&](uint32_t w, float m) {
        a0 = fmaf(m, bf2f((u16)(w & 0xffff)), a0);
        a1 = fmaf(m, bf2f((u16)(w >> 16)), a1);
    };
    acc_add(*(const uint32_t*)(xb + (size_t)row * FIN + fo));      // self loop
    int p  = __builtin_amdgcn_readfirstlane(rp[row]);
    int p1 = __builtin_amdgcn_readfirstlane(rp[row + 1]);
    for (; p + 8 <= p1; p += 8) {
        uint32_t v[8];
#pragma unroll
        for (int k = 0; k < 8; ++k) {
            int c = __builtin_amdgcn_readfirstlane(col[p + k]);
            v[k] = *(const uint32_t*)(xb + (size_t)c * FIN + fo);
        }
#pragma unroll
        for (int k = 0; k < 8; ++k) acc_add(v[k]);
    }
    int rem = p1 - p;
    if (rem) {
        uint32_t v[8];
#pragma unroll
        for (int k = 0; k < 8; ++k) {
            int idx = (k < rem) ? (p + k) : p;
            int c = __builtin_amdgcn_readfirstlane(col[idx]);
            v[k] = *(const uint32_t*)(xb + (size_t)c * FIN + fo);
        }
#pragma unroll
        for (int k = 0; k < 8; ++k) acc_fma(v[k], (k < rem) ? 1.f : 0.f);
    }
    uint32_t o = (uint32_t)f2bf(a0) | ((uint32_t)f2bf(a1) << 16);
    *(uint32_t*)(out + (size_t)row * FIN + fo) = o;
}

// ---------------- last layer: hs padded to 64 cols (bf16); agg + bias + log_softmax ----------------
// feature-parallel: lane owns 1 class (2 B), wave walks edges; softmax across lanes.
__global__ __launch_bounds__(256) void k_agg5(const u16* __restrict__ hs,
                                              const int* __restrict__ rp,
                                              const int* __restrict__ col,
                                              const float* __restrict__ dinv,
                                              const u16* __restrict__ bias,
                                              void* __restrict__ out,
                                              const int* __restrict__ flags) {
    int wq = __builtin_amdgcn_readfirstlane(threadIdx.x >> 6);
    int row = blockIdx.x * 4 + wq;
    if (row >= NN) return;
    int lane = threadIdx.x & 63;
    float a = bf2f(hs[(size_t)row * 64 + lane]);                   // self loop
    int p  = __builtin_amdgcn_readfirstlane(rp[row]);
    int p1 = __builtin_amdgcn_readfirstlane(rp[row + 1]);
    for (; p + 8 <= p1; p += 8) {
        u16 v[8];
#pragma unroll
        for (int k = 0; k < 8; ++k) {
            int c = __builtin_amdgcn_readfirstlane(col[p + k]);
            v[k] = hs[(size_t)c * 64 + lane];
        }
#pragma unroll
        for (int k = 0; k < 8; ++k) a += bf2f(v[k]);
    }
    int rem = p1 - p;
    if (rem) {
        u16 v[8];
#pragma unroll
        for (int k = 0; k < 8; ++k) {
            int idx = (k < rem) ? (p + k) : p;
            int c = __builtin_amdgcn_readfirstlane(col[idx]);
            v[k] = hs[(size_t)c * 64 + lane];
        }
#pragma unroll
        for (int k = 0; k < 8; ++k)
            a = fmaf((k < rem) ? 1.f : 0.f, bf2f(v[k]), a);
    }
    bool act = lane < NCLS;
    float d = dinv[row];
    float l = act ? fmaf(d, a, bf2f(bias[lane])) : -1e30f;
    float m = l;
#pragma unroll
    for (int off = 32; off > 0; off >>= 1) m = fmaxf(m, __shfl_xor(m, off));
    float e = act ? __expf(l - m) : 0.f;
#pragma unroll
    for (int off = 32; off > 0; off >>= 1) e += __shfl_xor(e, off);
    if (act) {
        float r = l - m - __logf(e);
        if (flags[0]) ((float*)out)[(size_t)row * NCLS + lane] = r;
        else          ((u16*)out)[(size_t)row * NCLS + lane] = f2bf(r);
    }
}

// ---------------- launch ----------------

extern "C" void kernel_launch(void* const* d_in, const int* in_sizes, int n_in,
                              void* d_out, int out_size, void* d_ws, size_t ws_size,
                              hipStream_t stream) {
    const void* x  = d_in[0];
    const int* ei  = (const int*)d_in[1];
    const void* W1 = d_in[2];
    const void* b1 = d_in[3];
    const void* W2 = d_in[4];
    const void* b2 = d_in[5];
    const void* W3 = d_in[6];
    const void* b3 = d_in[7];
    const void* W4 = d_in[8];
    const void* b4 = d_in[9];

    char* p = (char*)d_ws;
    auto alloc = [&](size_t b) -> char* {
        char* r = p;
        p += (b + 255) & ~(size_t)255;
        return r;
    };
    int*   flags = (int*)alloc(256);
    int*   cnt  = (int*)alloc((size_t)NN * 4);
    float* dinv = (float*)alloc((size_t)NN * 4);
    int*   rp   = (int*)alloc((size_t)(NN + 1) * 4);
    int*   col  = (int*)alloc((size_t)NE * 4);
    int*   bsum = (int*)alloc(4096);
    u16* xb  = (u16*)alloc((size_t)NN * FIN * 2);
    u16* W1t = (u16*)alloc((size_t)256 * 128 * 2);
    u16* W2t = (u16*)alloc((size_t)256 * 256 * 2);
    u16* W3t = (u16*)alloc((size_t)256 * 256 * 2);
    u16* W4t = (u16*)alloc((size_t)64 * 256 * 2);
    u16* bb1 = (u16*)alloc(512);
    u16* bb2 = (u16*)alloc(512);
    u16* bb3 = (u16*)alloc(512);
    u16* bb4 = (u16*)alloc(128);
    u16* bufA = (u16*)alloc((size_t)NN * HIDDEN * 2);
    u16* bufB = (u16*)alloc((size_t)NN * HIDDEN * 2);

    // CSR-build scratch aliased into conv buffers (dead before conv use)
    int* dst32   = (int*)bufA;                    // 6.4 MB
    int* src32   = dst32 + NE;                    // 6.4 MB
    int* partial = (int*)bufB;                    // 12.8 MB

    hipMemsetAsync(flags, 0, 16, stream);
    k_detect<<<64, 256, 0, stream>>>((const u16*)x, ei, flags);
    k_compact<<<(NE + 255) / 256, 256, 0, stream>>>(ei, dst32, src32, flags);

    // CSR build (atomic-free at device scope, i32 streams)
    k_histb<<<PRNG * SSL, 256, 0, stream>>>(dst32, partial);
    k_scan1<<<(NN + 1023) / 1024, 256, 0, stream>>>(partial, cnt, rp, bsum);
    k_scan2<<<1, 128, 0, stream>>>(bsum, (NN + 1023) / 1024);
    k_scan3o<<<(NN + 255) / 256, 256, 0, stream>>>(rp, bsum, cnt, dinv, partial);
    k_fillb<<<PRNG * SSL, 256, 0, stream>>>(dst32, src32, partial, col);

    // weights/bias transpose + x convert (prescaled by dinv, vectorized), one launch
    k_trans_cvt<<<705 + (NN * FIN / 8 + 255) / 256, 256, 0, stream>>>(
        W1, W2, W3, W4, W1t, W2t, W3t, W4t,
        b1, b2, b3, b4, bb1, bb2, bb3, bb4, x, dinv, xb, flags);

    dim3 gP(256, 2);    // 512 wg = 2 blocks/CU CO-RESIDENT (80KB LDS each) — do not shrink
    dim3 aggGrid((NN + 3) / 4);

    // conv1 (aggregate-then-transform): y = A_hat_scaled @ xb; h1 = relu(dinv*(y W1) + b1)
    k_aggx<<<aggGrid, 256, 0, stream>>>(xb, rp, col, bufB);
    k_gemmP<<<gP, 256, 0, stream>>>(bufB, W1t, dinv, bb1, bufA, 128, 0);
    // conv2: @ W2 -> hs in fp8, gather in fp8
    k_gemmP<<<gP, 256, 0, stream>>>(bufA, W2t, dinv, nullptr, bufB, 256, 1);
    k_agg8<<<aggGrid, 256, 0, stream>>>((const u8*)bufB, rp, col, dinv, bb2, bufA);
    // conv3: @ W2 (reused)
    k_gemmP<<<gP, 256, 0, stream>>>(bufA, W2t, dinv, nullptr, bufB, 256, 1);
    k_agg8<<<aggGrid, 256, 0, stream>>>((const u8*)bufB, rp, col, dinv, bb2, bufA);
    // conv4: @ W3
    k_gemmP<<<gP, 256, 0, stream>>>(bufA, W3t, dinv, nullptr, bufB, 256, 1);
    k_agg8<<<aggGrid, 256, 0, stream>>>((const u8*)bufB, rp, col, dinv, bb3, bufA);
    // conv5: @ W4 (persistent-B, padded to 64 cols, bf16) + fused log_softmax
    k_gemmP64<<<256, 256, 0, stream>>>(bufA, W4t, dinv, bufB);
    k_agg5<<<aggGrid, 256, 0, stream>>>(bufB, rp, col, dinv, bb4, d_out, flags);
}

// Round 11
// 648.250 us; speedup vs baseline: 1.1754x; 1.0364x over previous
//
#include <hip/hip_runtime.h>
#include <stdint.h>
#include <math.h>

#define NN   100000
#define FIN  128
#define HIDDEN 256
#define NCLS 40
#define NE   1600000

// CSR bucketing: P node-ranges x S edge-slices
#define PRNG 8
#define RNG  12500          // NN / PRNG
#define SSL  32
#define NES  50000          // NE / SSL

typedef unsigned short u16;
typedef unsigned char u8;
typedef __attribute__((ext_vector_type(8))) short s16x8;
typedef __attribute__((ext_vector_type(4))) float f32x4;
typedef __attribute__((ext_vector_type(2))) float f32x2;

__device__ __forceinline__ float bf2f(unsigned short u) {
    union { float f; uint32_t i; } v; v.i = ((uint32_t)u) << 16; return v.f;
}
__device__ __forceinline__ unsigned short f2bf(float f) {
    union { float f; uint32_t i; } v; v.f = f;
    uint32_t r = v.i + 0x7fffu + ((v.i >> 16) & 1u);
    return (unsigned short)(r >> 16);
}
__device__ __forceinline__ u8 f2fp8(float f) {
    int r = __builtin_amdgcn_cvt_pk_fp8_f32(f, f, 0, false);
    return (u8)(r & 0xff);
}

// LDS anti-bank-conflict swizzle for the [row][4 x 8u16] tiles (64B row stride):
// slot' = slot ^ S(row), S(row) = row[1] | (row[3]<<1).
// Staging threads (slot = t&3, row = t>>2): F(t) = t[3] | (t[5]<<1).
// Fragment reads (row bits 1,3 == lrow bits 1,3): G(lrow) = lrow[1] | (lrow[3]<<1).
// Source permutation == read permutation (involution) -> bijective per row; GLL dest stays linear.
#define SWZ_T(t)  ((((t) >> 3) & 1) | ((((t) >> 5) & 1) << 1))
#define SWZ_L(lr) ((((lr) >> 1) & 1) | ((((lr) >> 3) & 1) << 1))

// ---------------- dtype detection (parallel, 64 blocks) ----------------
// flags[0] != 0 => float tensors are float32 (else bf16)
// flags[2] == 0 => edge_index int64 (all odd i32 words zero), else int32
__global__ __launch_bounds__(256) void k_detect(const u16* __restrict__ x16,
                                                const int* __restrict__ ei,
                                                int* __restrict__ flags) {
    int g = blockIdx.x * 256 + threadIdx.x;      // 0..16383
    uint2 v = *(const uint2*)(x16 + (size_t)g * 4);
    int nan_cnt = 0;
    uint32_t w0 = v.x, w1 = v.y;
    if (((w0 >> 0)  & 0x7fff) >= 0x7f80) nan_cnt++;
    if (((w0 >> 16) & 0x7fff) >= 0x7f80) nan_cnt++;
    if (((w1 >> 0)  & 0x7fff) >= 0x7f80) nan_cnt++;
    if (((w1 >> 16) & 0x7fff) >= 0x7f80) nan_cnt++;
    int odd_nz = (g < 8192 && ei[2 * g + 1] != 0) ? 1 : 0;
#pragma unroll
    for (int off = 1; off < 64; off <<= 1) {
        nan_cnt += __shfl_xor(nan_cnt, off);
        odd_nz  += __shfl_xor(odd_nz, off);
    }
    if ((threadIdx.x & 63) == 0) {
        if (nan_cnt) atomicAdd(&flags[0], nan_cnt);
        if (odd_nz)  atomicAdd(&flags[2], odd_nz);
    }
}

// edge_index -> dense i32 dst/src (handles both i64 and i32 storage)
__global__ void k_compact(const int* __restrict__ ei, int* __restrict__ dst32,
                          int* __restrict__ src32, const int* __restrict__ flags) {
    int e = blockIdx.x * 256 + threadIdx.x;
    if (e < NE) {
        if (flags[2] == 0) { src32[e] = ei[2 * e]; dst32[e] = ei[2 * (NE + e)]; }
        else               { src32[e] = ei[e];     dst32[e] = ei[NE + e]; }
    }
}

// weights transpose + bias cvt + x cvt (prescaled by dinv, VECTORIZED x8), one launch
__global__ void k_trans_cvt(const void* W1, const void* W2, const void* W3, const void* W4,
                            u16* W1t, u16* W2t, u16* W3t, u16* W4t,
                            const void* b1, const void* b2, const void* b3, const void* b4,
                            u16* o1, u16* o2, u16* o3, u16* o4,
                            const void* __restrict__ x, const float* __restrict__ dinv,
                            u16* __restrict__ xb,
                            const int* __restrict__ flags) {
    int b = blockIdx.x;
    int fl = flags[0];
    int t = threadIdx.x;
    if (b >= 705) {            // x convert: 6250 blocks, 8 elems/thread
        int i8 = (b - 705) * 256 + t;
        if (i8 < NN * FIN / 8) {
            int i = i8 * 8;
            float d = dinv[i >> 7];          // 8 elems within one row (128 % 8 == 0)
            u16 r[8];
            if (fl) {
                const float* xf = (const float*)x + i;
                f32x4 v0 = *(const f32x4*)xf;
                f32x4 v1 = *(const f32x4*)(xf + 4);
#pragma unroll
                for (int k = 0; k < 4; ++k) { r[k] = f2bf(v0[k] * d); r[4 + k] = f2bf(v1[k] * d); }
            } else {
                uint4 v = *(const uint4*)((const u16*)x + i);
                uint32_t w[4] = {v.x, v.y, v.z, v.w};
#pragma unroll
                for (int k = 0; k < 4; ++k) {
                    r[2 * k]     = f2bf(bf2f((u16)(w[k] & 0xffff)) * d);
                    r[2 * k + 1] = f2bf(bf2f((u16)(w[k] >> 16)) * d);
                }
            }
            uint4 o;
            o.x = (uint32_t)r[0] | ((uint32_t)r[1] << 16);
            o.y = (uint32_t)r[2] | ((uint32_t)r[3] << 16);
            o.z = (uint32_t)r[4] | ((uint32_t)r[5] << 16);
            o.w = (uint32_t)r[6] | ((uint32_t)r[7] << 16);
            *(uint4*)(xb + i) = o;
        }
        return;
    }
    if (b == 704) {
        o1[t] = fl ? f2bf(((const float*)b1)[t]) : ((const u16*)b1)[t];
        o2[t] = fl ? f2bf(((const float*)b2)[t]) : ((const u16*)b2)[t];
        o3[t] = fl ? f2bf(((const float*)b3)[t]) : ((const u16*)b3)[t];
        if (t < 64) o4[t] = (t < NCLS) ? (fl ? f2bf(((const float*)b4)[t]) : ((const u16*)b4)[t]) : (u16)0;
        return;
    }
    const void* W; u16* Wt; int K, F, Fpad, base;
    if (b < 128)      { W = W1; Wt = W1t; K = 128; F = 256; Fpad = 256; base = 0; }
    else if (b < 384) { W = W2; Wt = W2t; K = 256; F = 256; Fpad = 256; base = 128; }
    else if (b < 640) { W = W3; Wt = W3t; K = 256; F = 256; Fpad = 256; base = 384; }
    else              { W = W4; Wt = W4t; K = 256; F = 40;  Fpad = 64;  base = 640; }
    int idx = (b - base) * 256 + t;
    if (idx >= K * Fpad) return;
    int f = idx / K, k = idx - f * K;
    u16 v = 0;
    if (f < F) {
        if (fl) v = f2bf(((const float*)W)[(size_t)k * F + f]);
        else    v = ((const u16*)W)[(size_t)k * F + f];
    }
    Wt[idx] = v;
}

// ---------------- CSR build (no device atomics; i32 inputs) ----------------

__global__ __launch_bounds__(256) void k_histb(const int* __restrict__ dst32,
                                               int* __restrict__ partial) {
    __shared__ int h[RNG];
    int p = blockIdx.x >> 5, s = blockIdx.x & 31;
    int t = threadIdx.x;
    int4 z4 = make_int4(0, 0, 0, 0);
    for (int i = t * 4; i < RNG; i += 1024) *(int4*)(h + i) = z4;
    __syncthreads();
    int base = s * NES;
    int lo = p * RNG;
    int nfull = NES & ~1023;
    for (int k = t * 4; k < nfull; k += 1024) {
        int4 d4 = *(const int4*)(dst32 + base + k);
        int a;
        a = d4.x - lo; if ((unsigned)a < RNG) atomicAdd(&h[a], 1);
        a = d4.y - lo; if ((unsigned)a < RNG) atomicAdd(&h[a], 1);
        a = d4.z - lo; if ((unsigned)a < RNG) atomicAdd(&h[a], 1);
        a = d4.w - lo; if ((unsigned)a < RNG) atomicAdd(&h[a], 1);
    }
    for (int k = nfull + t; k < NES; k += 256) {
        int a = dst32[base + k] - lo;
        if ((unsigned)a < RNG) atomicAdd(&h[a], 1);
    }
    __syncthreads();
    int* out = partial + blockIdx.x * RNG;
    for (int i = t * 4; i < RNG; i += 1024) *(int4*)(out + i) = *(const int4*)(h + i);
}

// fused: per-node degree (sum of 32 partial slices) + block-local exclusive prefix
__global__ __launch_bounds__(256) void k_scan1(const int* __restrict__ partial,
                                               int* __restrict__ cnt,
                                               int* __restrict__ out,
                                               int* __restrict__ bsum) {
    __shared__ int sh[256];
    int t = threadIdx.x;
    int base = blockIdx.x * 1024 + t * 4;
    int v0 = 0, v1 = 0, v2 = 0, v3 = 0;
    if (base < NN) {
        int p = base / RNG, il = base - p * RNG;
        const int* q = partial + (p * SSL) * RNG + il;
        int4 acc = make_int4(0, 0, 0, 0);
#pragma unroll
        for (int s = 0; s < SSL; ++s) {
            int4 w = *(const int4*)(q + s * RNG);
            acc.x += w.x; acc.y += w.y; acc.z += w.z; acc.w += w.w;
        }
        v0 = acc.x; v1 = acc.y; v2 = acc.z; v3 = acc.w;
        *(int4*)(cnt + base) = acc;
    }
    int s = v0 + v1 + v2 + v3;
    sh[t] = s;
    __syncthreads();
    for (int off = 1; off < 256; off <<= 1) {
        int x = (t >= off) ? sh[t - off] : 0;
        __syncthreads();
        sh[t] += x;
        __syncthreads();
    }
    int ex = sh[t] - s;
    if (base < NN) {
        int4 o = make_int4(ex, ex + v0, ex + v0 + v1, ex + v0 + v1 + v2);
        *(int4*)(out + base) = o;
    }
    if (t == 255) bsum[blockIdx.x] = sh[255];
}

// parallel exclusive scan of nb (<=128) block sums
__global__ void k_scan2(int* bsum, int nb) {
    __shared__ int sh[128];
    int t = threadIdx.x;
    int v = (t < nb) ? bsum[t] : 0;
    sh[t] = v;
    __syncthreads();
    for (int off = 1; off < 128; off <<= 1) {
        int x = (t >= off) ? sh[t - off] : 0;
        __syncthreads();
        sh[t] += x;
        __syncthreads();
    }
    if (t < nb) bsum[t] = sh[t] - v;
}

// finalize rp, dinv, and convert partial -> absolute slice offsets
__global__ void k_scan3o(int* __restrict__ rp, const int* __restrict__ bsum,
                         const int* __restrict__ cnt, float* __restrict__ dinv,
                         int* __restrict__ partial) {
    int i = blockIdx.x * 256 + threadIdx.x;
    if (i < NN) {
        int v = rp[i] + bsum[i >> 10];
        rp[i] = v;
        dinv[i] = rsqrtf((float)(cnt[i] + 1));
        int p = i / RNG, il = i - p * RNG;
        int* q = partial + (p * SSL) * RNG + il;
        int run = v;
#pragma unroll
        for (int s = 0; s < SSL; ++s) { int t = q[s * RNG]; q[s * RNG] = run; run += t; }
    }
    if (i == 0) rp[NN] = NE;
}

__global__ __launch_bounds__(256) void k_fillb(const int* __restrict__ dst32,
                                               const int* __restrict__ src32,
                                               const int* __restrict__ offs,
                                               int* __restrict__ col) {
    __shared__ int h[RNG];
    int p = blockIdx.x >> 5, s = blockIdx.x & 31;
    int t = threadIdx.x;
    const int* o = offs + blockIdx.x * RNG;
    for (int i = t * 4; i < RNG; i += 1024) *(int4*)(h + i) = *(const int4*)(o + i);
    __syncthreads();
    int base = s * NES;
    int lo = p * RNG;
    int nfull = NES & ~1023;
    for (int k = t * 4; k < nfull; k += 1024) {
        int4 d4 = *(const int4*)(dst32 + base + k);
        int4 s4 = *(const int4*)(src32 + base + k);
        int a;
        a = d4.x - lo; if ((unsigned)a < RNG) col[atomicAdd(&h[a], 1)] = s4.x;
        a = d4.y - lo; if ((unsigned)a < RNG) col[atomicAdd(&h[a], 1)] = s4.y;
        a = d4.z - lo; if ((unsigned)a < RNG) col[atomicAdd(&h[a], 1)] = s4.z;
        a = d4.w - lo; if ((unsigned)a < RNG) col[atomicAdd(&h[a], 1)] = s4.w;
    }
    for (int k = nfull + t; k < NES; k += 256) {
        int a = dst32[base + k] - lo;
        if ((unsigned)a < RNG) col[atomicAdd(&h[a], 1)] = src32[base + k];
    }
}

// ---------------- Persistent-B GEMM (N=256 in 4 x 64-col tiles): C = epi(A @ Wt^T) ----------
// out_fp8: write hs as fp8 e4m3 (for the gather kernels); else bf16.
// LDS = Bs 32KB + As 16KB = 48KB -> 3 blocks/CU co-resident (144KB of 160KB).
// Grid (192,4) = 768 wg = exactly 3/CU. r8/r9 measured co-residency is the
// latency-hiding mechanism for the per-kt global_load_lds drain (1->2 blk: 68->52us).
// LDS slot-swizzle (SWZ_*) kills the 8-way bank conflict on ds_read_b128 (r10).

#define GLL(g, l) __builtin_amdgcn_global_load_lds( \
    (const __attribute__((address_space(1))) unsigned int*)(g), \
    (__attribute__((address_space(3))) unsigned int*)(l), 16, 0, 0)

#define NT128 ((NN + 127) / 128)
#define NT256 ((NN + 255) / 256)

__global__ __launch_bounds__(256) void k_gemmP(const u16* __restrict__ A,
                                               const u16* __restrict__ Wt,
                                               const float* __restrict__ dinv,
                                               const u16* __restrict__ bias,
                                               u16* __restrict__ C,
                                               int K, int out_fp8) {
    __shared__ __align__(16) u16 Bs[64 * 256];    // 32KB max: blocked [K/32][64][4 slots x 8]
    __shared__ __align__(16) u16 As[2 * 128 * 32];// 16KB, double-buffered
    int t = threadIdx.x;
    int bn = blockIdx.y;                          // 0..3: 64-col tile
    int w = t >> 6, lane = t & 63;                // w = wave = 32-row group
    int lrow = lane & 15, lq = lane >> 4;
    int r0 = t >> 2;
    int seg = ((t & 3) ^ SWZ_T(t)) * 8;           // pre-swizzled global source segment
    int lqs = (lq ^ SWZ_L(lrow)) * 8;             // swizzled LDS read slot (per-lane const)

    int nK = K >> 5;
    // stage B: one kt-block (64 rows x 64B) per round; row = t>>2, slot = t&3
    for (int r = 0; r < nK; ++r)
        GLL(Wt + (size_t)(bn * 64 + (t >> 2)) * K + r * 32 + seg, Bs + r * 2048 + t * 8);

    bool fuse = (bias != nullptr);
    float bcol[4];
#pragma unroll
    for (int j = 0; j < 4; ++j)
        bcol[j] = fuse ? bf2f(bias[bn * 64 + j * 16 + lrow]) : 0.f;

    for (int tm = blockIdx.x; tm < NT128; tm += gridDim.x) {
        int rowBase = tm * 128;
        int ar0 = rowBase + r0;       if (ar0 > NN - 1) ar0 = NN - 1;
        int ar1 = rowBase + 64 + r0;  if (ar1 > NN - 1) ar1 = NN - 1;
        const u16* a0p = A + (size_t)ar0 * K + seg;
        const u16* a1p = A + (size_t)ar1 * K + seg;
        GLL(a0p, As + t * 8);
        GLL(a1p, As + 2048 + t * 8);

        f32x4 acc[2][4] = {};
        int cur = 0;
        for (int kt = 0; kt < nK; ++kt) {
            __syncthreads();
            if (kt + 1 < nK) {
                int nxt = cur ^ 1;
                GLL(a0p + (kt + 1) * 32, As + nxt * 4096 + t * 8);
                GLL(a1p + (kt + 1) * 32, As + nxt * 4096 + 2048 + t * 8);
            }
            const u16* ab = As + cur * 4096;
            const u16* bb = Bs + kt * 2048;
            s16x8 af[2], bf[4];
#pragma unroll
            for (int i = 0; i < 2; ++i)
                af[i] = *(const s16x8*)(ab + (w * 32 + i * 16 + lrow) * 32 + lqs);
#pragma unroll
            for (int j = 0; j < 4; ++j)
                bf[j] = *(const s16x8*)(bb + (j * 16 + lrow) * 32 + lqs);
#pragma unroll
            for (int i = 0; i < 2; ++i)
#pragma unroll
                for (int j = 0; j < 4; ++j)
                    acc[i][j] = __builtin_amdgcn_mfma_f32_16x16x32_bf16(af[i], bf[j], acc[i][j], 0, 0, 0);
            cur ^= 1;
        }

        u8* C8 = (u8*)C;
#pragma unroll
        for (int i = 0; i < 2; ++i) {
#pragma unroll
            for (int rr = 0; rr < 4; ++rr) {
                int row = rowBase + w * 32 + i * 16 + lq * 4 + rr;
                if (row < NN) {
                    float d = dinv[row];
#pragma unroll
                    for (int j = 0; j < 4; ++j) {
                        int colg = bn * 64 + j * 16 + lrow;
                        float v = fuse ? fmaxf(fmaf(d, acc[i][j][rr], bcol[j]), 0.f)
                                       : acc[i][j][rr] * d;
                        if (out_fp8) C8[(size_t)row * HIDDEN + colg] = f2fp8(v);
                        else         C[(size_t)row * HIDDEN + colg] = f2bf(v);
                    }
                }
            }
        }
        __syncthreads();
    }
}

// ---------------- Persistent-B GEMM conv5: 256-row x 64-col tiles, K=256 ----------------
__global__ __launch_bounds__(256) void k_gemmP64(const u16* __restrict__ A,
                                                 const u16* __restrict__ Wt,
                                                 const float* __restrict__ dinv,
                                                 u16* __restrict__ C) {
    const int K = 256;
    __shared__ __align__(16) u16 Bs[64 * 256];
    __shared__ __align__(16) u16 As[2 * 256 * 32];
    int t = threadIdx.x;
    int w = t >> 6, lane = t & 63;
    int lrow = lane & 15, lq = lane >> 4;
    int seg = ((t & 3) ^ SWZ_T(t)) * 8;
    int lqs = (lq ^ SWZ_L(lrow)) * 8;
    int rr0 = t >> 2;

    for (int r = 0; r < 8; ++r)
        GLL(Wt + (size_t)(t >> 2) * K + r * 32 + seg, Bs + r * 2048 + t * 8);

    for (int tm = blockIdx.x; tm < NT256; tm += gridDim.x) {
        int rowBase = tm * 256;
        const u16* ap[4];
#pragma unroll
        for (int c = 0; c < 4; ++c) {
            int ar = rowBase + c * 64 + rr0;
            if (ar > NN - 1) ar = NN - 1;
            ap[c] = A + (size_t)ar * K + seg;
        }
#pragma unroll
        for (int c = 0; c < 4; ++c) GLL(ap[c], As + c * 2048 + t * 8);

        f32x4 acc[4][4] = {};
        int cur = 0;
        for (int kt = 0; kt < 8; ++kt) {
            __syncthreads();
            if (kt + 1 < 8) {
                int nxt = cur ^ 1;
#pragma unroll
                for (int c = 0; c < 4; ++c)
                    GLL(ap[c] + (kt + 1) * 32, As + nxt * 8192 + c * 2048 + t * 8);
            }
            const u16* ab = As + cur * 8192;
            const u16* bb = Bs + kt * 2048;
            s16x8 af[4], bf[4];
#pragma unroll
            for (int i = 0; i < 4; ++i)
                af[i] = *(const s16x8*)(ab + (w * 64 + i * 16 + lrow) * 32 + lqs);
#pragma unroll
            for (int j = 0; j < 4; ++j)
                bf[j] = *(const s16x8*)(bb + (j * 16 + lrow) * 32 + lqs);
#pragma unroll
            for (int i = 0; i < 4; ++i)
#pragma unroll
                for (int j = 0; j < 4; ++j)
                    acc[i][j] = __builtin_amdgcn_mfma_f32_16x16x32_bf16(af[i], bf[j], acc[i][j], 0, 0, 0);
            cur ^= 1;
        }

#pragma unroll
        for (int i = 0; i < 4; ++i) {
#pragma unroll
            for (int rr = 0; rr < 4; ++rr) {
                int row = rowBase + w * 64 + i * 16 + lq * 4 + rr;
                if (row < NN) {
                    float d = dinv[row];
#pragma unroll
                    for (int j = 0; j < 4; ++j) {
                        int colg = j * 16 + lrow;
                        C[(size_t)row * 64 + colg] = f2bf(acc[i][j][rr] * d);
                    }
                }
            }
        }
        __syncthreads();
    }
}

// ---------------- aggregation F=256 over fp8 hs (convs 2-4) ----------------
// feature-parallel full wave: lane owns 4 fp8 features (4 B), wave walks edges.
// row/p/col are wave-uniform -> scalar loads; 8 gathers in flight (measured optimum).

__global__ __launch_bounds__(256) void k_agg8(const u8* __restrict__ hs,
                                              const int* __restrict__ rp,
                                              const int* __restrict__ col,
                                              const float* __restrict__ dinv,
                                              const u16* __restrict__ bias,
                                              u16* __restrict__ out) {
    int wq = __builtin_amdgcn_readfirstlane(threadIdx.x >> 6);
    int row = blockIdx.x * 4 + wq;
    if (row >= NN) return;
    int lane = threadIdx.x & 63;
    int fo = lane * 4;                  // feature offset (fp8: bytes == features)
    float a0 = 0.f, a1 = 0.f, a2 = 0.f, a3 = 0.f;
    auto acc_add = [&](uint32_t w) {
        f32x2 x = __builtin_amdgcn_cvt_pk_f32_fp8(w, false);
        f32x2 y = __builtin_amdgcn_cvt_pk_f32_fp8(w, true);
        a0 += x.x; a1 += x.y; a2 += y.x; a3 += y.y;
    };
    auto acc_fma = [&](uint32_t w, float m) {
        f32x2 x = __builtin_amdgcn_cvt_pk_f32_fp8(w, false);
        f32x2 y = __builtin_amdgcn_cvt_pk_f32_fp8(w, true);
        a0 = fmaf(m, x.x, a0); a1 = fmaf(m, x.y, a1);
        a2 = fmaf(m, y.x, a2); a3 = fmaf(m, y.y, a3);
    };
    acc_add(*(const uint32_t*)(hs + (size_t)row * HIDDEN + fo));   // self loop
    int p  = __builtin_amdgcn_readfirstlane(rp[row]);
    int p1 = __builtin_amdgcn_readfirstlane(rp[row + 1]);
    for (; p + 8 <= p1; p += 8) {
        uint32_t v[8];
#pragma unroll
        for (int k = 0; k < 8; ++k) {
            int c = __builtin_amdgcn_readfirstlane(col[p + k]);
            v[k] = *(const uint32_t*)(hs + (size_t)c * HIDDEN + fo);
        }
#pragma unroll
        for (int k = 0; k < 8; ++k) acc_add(v[k]);
    }
    int rem = p1 - p;                   // 0..7, wave-uniform
    if (rem) {
        uint32_t v[8];
#pragma unroll
        for (int k = 0; k < 8; ++k) {
            int idx = (k < rem) ? (p + k) : p;
            int c = __builtin_amdgcn_readfirstlane(col[idx]);
            v[k] = *(const uint32_t*)(hs + (size_t)c * HIDDEN + fo);
        }
#pragma unroll
        for (int k = 0; k < 8; ++k) acc_fma(v[k], (k < rem) ? 1.f : 0.f);
    }
    float d = dinv[row];
    uint2 bv = *(const uint2*)(bias + fo);
    float r0 = fmaxf(fmaf(d, a0, bf2f((u16)(bv.x & 0xffff))), 0.f);
    float r1 = fmaxf(fmaf(d, a1, bf2f((u16)(bv.x >> 16))), 0.f);
    float r2 = fmaxf(fmaf(d, a2, bf2f((u16)(bv.y & 0xffff))), 0.f);
    float r3 = fmaxf(fmaf(d, a3, bf2f((u16)(bv.y >> 16))), 0.f);
    uint2 o;
    o.x = (uint32_t)f2bf(r0) | ((uint32_t)f2bf(r1) << 16);
    o.y = (uint32_t)f2bf(r2) | ((uint32_t)f2bf(r3) << 16);
    *(uint2*)(out + (size_t)row * HIDDEN + fo) = o;
}

// ---------------- conv1 pre-aggregation on prescaled x (128 features, bf16) ----------------
// feature-parallel: lane owns 2 bf16 features (4 B), wave walks edges; 8 in flight.
__global__ __launch_bounds__(256) void k_aggx(const u16* __restrict__ xb,
                                              const int* __restrict__ rp,
                                              const int* __restrict__ col,
                                              u16* __restrict__ out) {
    int wq = __builtin_amdgcn_readfirstlane(threadIdx.x >> 6);
    int row = blockIdx.x * 4 + wq;
    if (row >= NN) return;
    int lane = threadIdx.x & 63;
    int fo = lane * 2;                  // u16 index: 2 bf16 per lane
    float a0 = 0.f, a1 = 0.f;
    auto acc_add = [&](uint32_t w) {
        a0 += bf2f((u16)(w & 0xffff));
        a1 += bf2f((u16)(w >> 16));
    };
    auto acc_fma = [&](uint32_t w, float m) {
        a0 = fmaf(m, bf2f((u16)(w & 0xffff)), a0);
        a1 = fmaf(m, bf2f((u16)(w >> 16)), a1);
    };
    acc_add(*(const uint32_t*)(xb + (size_t)row * FIN + fo));      // self loop
    int p  = __builtin_amdgcn_readfirstlane(rp[row]);
    int p1 = __builtin_amdgcn_readfirstlane(rp[row + 1]);
    for (; p + 8 <= p1; p += 8) {
        uint32_t v[8];
#pragma unroll
        for (int k = 0; k < 8; ++k) {
            int c = __builtin_amdgcn_readfirstlane(col[p + k]);
            v[k] = *(const uint32_t*)(xb + (size_t)c * FIN + fo);
        }
#pragma unroll
        for (int k = 0; k < 8; ++k) acc_add(v[k]);
    }
    int rem = p1 - p;
    if (rem) {
        uint32_t v[8];
#pragma unroll
        for (int k = 0; k < 8; ++k) {
            int idx = (k < rem) ? (p + k) : p;
            int c = __builtin_amdgcn_readfirstlane(col[idx]);
            v[k] = *(const uint32_t*)(xb + (size_t)c * FIN + fo);
        }
#pragma unroll
        for (int k = 0; k < 8; ++k) acc_fma(v[k], (k < rem) ? 1.f : 0.f);
    }
    uint32_t o = (uint32_t)f2bf(a0) | ((uint32_t)f2bf(a1) << 16);
    *(uint32_t*)(out + (size_t)row * FIN + fo) = o;
}

// ---------------- last layer: hs padded to 64 cols (bf16); agg + bias + log_softmax ----------------
// feature-parallel: lane owns 1 class (2 B), wave walks edges; softmax across lanes.
__global__ __launch_bounds__(256) void k_agg5(const u16* __restrict__ hs,
                                              const int* __restrict__ rp,
                                              const int* __restrict__ col,
                                              const float* __restrict__ dinv,
                                              const u16* __restrict__ bias,
                                              void* __restrict__ out,
                                              const int* __restrict__ flags) {
    int wq = __builtin_amdgcn_readfirstlane(threadIdx.x >> 6);
    int row = blockIdx.x * 4 + wq;
    if (row >= NN) return;
    int lane = threadIdx.x & 63;
    float a = bf2f(hs[(size_t)row * 64 + lane]);                   // self loop
    int p  = __builtin_amdgcn_readfirstlane(rp[row]);
    int p1 = __builtin_amdgcn_readfirstlane(rp[row + 1]);
    for (; p + 8 <= p1; p += 8) {
        u16 v[8];
#pragma unroll
        for (int k = 0; k < 8; ++k) {
            int c = __builtin_amdgcn_readfirstlane(col[p + k]);
            v[k] = hs[(size_t)c * 64 + lane];
        }
#pragma unroll
        for (int k = 0; k < 8; ++k) a += bf2f(v[k]);
    }
    int rem = p1 - p;
    if (rem) {
        u16 v[8];
#pragma unroll
        for (int k = 0; k < 8; ++k) {
            int idx = (k < rem) ? (p + k) : p;
            int c = __builtin_amdgcn_readfirstlane(col[idx]);
            v[k] = hs[(size_t)c * 64 + lane];
        }
#pragma unroll
        for (int k = 0; k < 8; ++k)
            a = fmaf((k < rem) ? 1.f : 0.f, bf2f(v[k]), a);
    }
    bool act = lane < NCLS;
    float d = dinv[row];
    float l = act ? fmaf(d, a, bf2f(bias[lane])) : -1e30f;
    float m = l;
#pragma unroll
    for (int off = 32; off > 0; off >>= 1) m = fmaxf(m, __shfl_xor(m, off));
    float e = act ? __expf(l - m) : 0.f;
#pragma unroll
    for (int off = 32; off > 0; off >>= 1) e += __shfl_xor(e, off);
    if (act) {
        float r = l - m - __logf(e);
        if (flags[0]) ((float*)out)[(size_t)row * NCLS + lane] = r;
        else          ((u16*)out)[(size_t)row * NCLS + lane] = f2bf(r);
    }
}

// ---------------- launch ----------------

extern "C" void kernel_launch(void* const* d_in, const int* in_sizes, int n_in,
                              void* d_out, int out_size, void* d_ws, size_t ws_size,
                              hipStream_t stream) {
    const void* x  = d_in[0];
    const int* ei  = (const int*)d_in[1];
    const void* W1 = d_in[2];
    const void* b1 = d_in[3];
    const void* W2 = d_in[4];
    const void* b2 = d_in[5];
    const void* W3 = d_in[6];
    const void* b3 = d_in[7];
    const void* W4 = d_in[8];
    const void* b4 = d_in[9];

    char* p = (char*)d_ws;
    auto alloc = [&](size_t b) -> char* {
        char* r = p;
        p += (b + 255) & ~(size_t)255;
        return r;
    };
    int*   flags = (int*)alloc(256);
    int*   cnt  = (int*)alloc((size_t)NN * 4);
    float* dinv = (float*)alloc((size_t)NN * 4);
    int*   rp   = (int*)alloc((size_t)(NN + 1) * 4);
    int*   col  = (int*)alloc((size_t)NE * 4);
    int*   bsum = (int*)alloc(4096);
    u16* xb  = (u16*)alloc((size_t)NN * FIN * 2);
    u16* W1t = (u16*)alloc((size_t)256 * 128 * 2);
    u16* W2t = (u16*)alloc((size_t)256 * 256 * 2);
    u16* W3t = (u16*)alloc((size_t)256 * 256 * 2);
    u16* W4t = (u16*)alloc((size_t)64 * 256 * 2);
    u16* bb1 = (u16*)alloc(512);
    u16* bb2 = (u16*)alloc(512);
    u16* bb3 = (u16*)alloc(512);
    u16* bb4 = (u16*)alloc(128);
    u16* bufA = (u16*)alloc((size_t)NN * HIDDEN * 2);
    u16* bufB = (u16*)alloc((size_t)NN * HIDDEN * 2);

    // CSR-build scratch aliased into conv buffers (dead before conv use)
    int* dst32   = (int*)bufA;                    // 6.4 MB
    int* src32   = dst32 + NE;                    // 6.4 MB
    int* partial = (int*)bufB;                    // 12.8 MB

    hipMemsetAsync(flags, 0, 16, stream);
    k_detect<<<64, 256, 0, stream>>>((const u16*)x, ei, flags);
    k_compact<<<(NE + 255) / 256, 256, 0, stream>>>(ei, dst32, src32, flags);

    // CSR build (atomic-free at device scope, i32 streams)
    k_histb<<<PRNG * SSL, 256, 0, stream>>>(dst32, partial);
    k_scan1<<<(NN + 1023) / 1024, 256, 0, stream>>>(partial, cnt, rp, bsum);
    k_scan2<<<1, 128, 0, stream>>>(bsum, (NN + 1023) / 1024);
    k_scan3o<<<(NN + 255) / 256, 256, 0, stream>>>(rp, bsum, cnt, dinv, partial);
    k_fillb<<<PRNG * SSL, 256, 0, stream>>>(dst32, src32, partial, col);

    // weights/bias transpose + x convert (prescaled by dinv, vectorized), one launch
    k_trans_cvt<<<705 + (NN * FIN / 8 + 255) / 256, 256, 0, stream>>>(
        W1, W2, W3, W4, W1t, W2t, W3t, W4t,
        b1, b2, b3, b4, bb1, bb2, bb3, bb4, x, dinv, xb, flags);

    dim3 gP(192, 4);    // 768 wg = 3 blocks/CU CO-RESIDENT (48KB LDS each)
    dim3 aggGrid((NN + 3) / 4);

    // conv1 (aggregate-then-transform): y = A_hat_scaled @ xb; h1 = relu(dinv*(y W1) + b1)
    k_aggx<<<aggGrid, 256, 0, stream>>>(xb, rp, col, bufB);
    k_gemmP<<<gP, 256, 0, stream>>>(bufB, W1t, dinv, bb1, bufA, 128, 0);
    // conv2: @ W2 -> hs in fp8, gather in fp8
    k_gemmP<<<gP, 256, 0, stream>>>(bufA, W2t, dinv, nullptr, bufB, 256, 1);
    k_agg8<<<aggGrid, 256, 0, stream>>>((const u8*)bufB, rp, col, dinv, bb2, bufA);
    // conv3: @ W2 (reused)
    k_gemmP<<<gP, 256, 0, stream>>>(bufA, W2t, dinv, nullptr, bufB, 256, 1);
    k_agg8<<<aggGrid, 256, 0, stream>>>((const u8*)bufB, rp, col, dinv, bb2, bufA);
    // conv4: @ W3
    k_gemmP<<<gP, 256, 0, stream>>>(bufA, W3t, dinv, nullptr, bufB, 256, 1);
    k_agg8<<<aggGrid, 256, 0, stream>>>((const u8*)bufB, rp, col, dinv, bb3, bufA);
    // conv5: @ W4 (persistent-B, padded to 64 cols, bf16) + fused log_softmax
    k_gemmP64<<<256, 256, 0, stream>>>(bufA, W4t, dinv, bufB);
    k_agg5<<<aggGrid, 256, 0, stream>>>(bufB, rp, col, dinv, bb4, d_out, flags);
}